// Round 11
// baseline (1146.368 us; speedup 1.0000x reference)
//
#include <hip/hip_runtime.h>

#define NN 100000
#define EE 640000
#define GG 256
#define LL 3
#define HH 128

constexpr int BM = 64;   // rows per block (node gemms)
constexpr int BK = 16;   // k-chunk (fp32 gemm, legacy)

typedef _Float16 f16;
typedef f16 f16x8 __attribute__((ext_vector_type(8)));
typedef f16 f16x4 __attribute__((ext_vector_type(4)));
typedef f16 f16x2 __attribute__((ext_vector_type(2)));
typedef float f32x4 __attribute__((ext_vector_type(4)));

// padded row stride (halfs) for transposed weight / activation tiles.
// 136 halfs = 272 B = 68 words; 68 % 32 = 4 -> fragment rows land 4 banks
// apart; a wave's b128 fragment read hits the 8-words/bank optimum.
#define TSTR 136

// async global->LDS, 16 B per lane (gfx950). Dest must be linear in lane
// order: HW uses wave-uniform base + lane*16 (m104). Our staging is a
// straight contiguous copy, so per-lane dst = base + tid*16 is exactly that.
__device__ __forceinline__ void gload_lds16(const void* g, void* l) {
  __builtin_amdgcn_global_load_lds(
      (const __attribute__((address_space(1))) void*)g,
      (__attribute__((address_space(3))) void*)l, 16, 0, 0);
}

// ---------------------------------------------------------------------------
// LEGACY fp32 tiled GEMM (verified in the 2897us kernel). Kept uninstantiated
// as a revert path for bisection; costs nothing when unused.
// ---------------------------------------------------------------------------
template <int MODE>
__global__ __launch_bounds__(256) void gemm_k(
    const float* __restrict__ X, const float* __restrict__ W,
    const float* __restrict__ bias, float* __restrict__ out, int M, int K,
    const float* __restrict__ X2, const float* __restrict__ inv) {
  __shared__ __align__(16) float Xs[BK][BM];
  __shared__ __align__(16) float Ws[BK][HH];

  const int tid = threadIdx.x;
  const int m0 = blockIdx.x * BM;
  const int tm = (tid >> 4) << 2;
  const int tn = (tid & 15) << 3;
  const int xr = tid >> 2;
  const int xc = (tid & 3) << 2;

  float acc[4][8];
#pragma unroll
  for (int i = 0; i < 4; ++i)
#pragma unroll
    for (int j = 0; j < 8; ++j) acc[i][j] = 0.f;

  for (int k0 = 0; k0 < K; k0 += BK) {
    float4 xv = make_float4(0.f, 0.f, 0.f, 0.f);
    if (m0 + xr < M) {
      if (MODE == 3) {
        if (k0 < HH) {
          xv = *(const float4*)(X + (size_t)(m0 + xr) * HH + k0 + xc);
        } else {
          xv = *(const float4*)(X2 + (size_t)(m0 + xr) * HH + (k0 - HH) + xc);
          const float s = inv[m0 + xr];
          xv.x *= s; xv.y *= s; xv.z *= s; xv.w *= s;
        }
      } else {
        xv = *(const float4*)(X + (size_t)(m0 + xr) * K + k0 + xc);
      }
    }
    Xs[xc + 0][xr] = xv.x;
    Xs[xc + 1][xr] = xv.y;
    Xs[xc + 2][xr] = xv.z;
    Xs[xc + 3][xr] = xv.w;
#pragma unroll
    for (int i = 0; i < 2; ++i) {
      const int q = tid + i * 256;
      const int row = q >> 5;
      const int c4 = (q & 31) << 2;
      *(float4*)&Ws[row][c4] =
          *(const float4*)(W + (size_t)(k0 + row) * HH + c4);
    }
    __syncthreads();
#pragma unroll
    for (int k = 0; k < BK; ++k) {
      const float4 x4 = *(const float4*)&Xs[k][tm];
      const float4 w0 = *(const float4*)&Ws[k][tn];
      const float4 w1 = *(const float4*)&Ws[k][tn + 4];
      const float xr_[4] = {x4.x, x4.y, x4.z, x4.w};
      const float wr_[8] = {w0.x, w0.y, w0.z, w0.w, w1.x, w1.y, w1.z, w1.w};
#pragma unroll
      for (int i = 0; i < 4; ++i)
#pragma unroll
        for (int j = 0; j < 8; ++j)
          acc[i][j] = fmaf(xr_[i], wr_[j], acc[i][j]);
    }
    __syncthreads();
  }

#pragma unroll
  for (int i = 0; i < 4; ++i) {
    const int r = m0 + tm + i;
    if (r >= M) continue;
    float o[8];
#pragma unroll
    for (int j = 0; j < 8; ++j) {
      float v = acc[i][j];
      if (MODE == 1 || MODE == 3) {
        v += bias[tn + j];
        v = v > 0.f ? v : 0.f;
      }
      o[j] = v;
    }
    float4* d4 = (float4*)(out + (size_t)r * HH + tn);
    d4[0] = make_float4(o[0], o[1], o[2], o[3]);
    d4[1] = make_float4(o[4], o[5], o[6], o[7]);
  }
}

// ---------------------------------------------------------------------------
// Weight prep: transpose + fp16-convert + zero-pad ALL weights once into a
// 22-buffer arena of [128 n][TSTR k] halfs (single launch):
//   0:      We0^T          (K=16, msg encoder; k>=16 zero -> K=32 pad works)
//   1..2:   We[l]^T        l=0,1 (msg chain layers)
//   3..5:   WMe[l]^T       = (WM[l] + 2*H*H)^T, l=0..2 (msg projection)
//   6:      Wn0^T          (K=64, node encoder)
//   7..9:   WM1[l]^T       (A projection, dst), l=0..2
//   10..12: WM2[l]^T       (B projection, src)
//   13..15: Wn[l]^T
//   16..21: WU[l]^T        chunks: 16+2l = rows 0..127 (h part),
//                          17+2l = rows 128..255 (agg part)
// ---------------------------------------------------------------------------
__global__ void prep_w(const float* __restrict__ We0,
                       const float* __restrict__ We,
                       const float* __restrict__ WM,
                       const float* __restrict__ Wn0,
                       const float* __restrict__ Wn,
                       const float* __restrict__ WU, f16* __restrict__ out) {
  const int buf = blockIdx.x >> 3;
  const int rowg = blockIdx.x & 7;  // 16 n-rows per block
  const float* src;
  int K;
  if (buf == 0) {
    src = We0; K = 16;
  } else if (buf <= 2) {
    src = We + (size_t)(buf - 1) * HH * HH; K = HH;
  } else if (buf <= 5) {
    src = WM + (size_t)(buf - 3) * 3 * HH * HH + 2 * HH * HH; K = HH;
  } else if (buf == 6) {
    src = Wn0; K = 64;
  } else if (buf <= 9) {
    src = WM + (size_t)(buf - 7) * 3 * HH * HH; K = HH;
  } else if (buf <= 12) {
    src = WM + (size_t)(buf - 10) * 3 * HH * HH + HH * HH; K = HH;
  } else if (buf <= 15) {
    src = Wn + (size_t)(buf - 13) * HH * HH; K = HH;
  } else {
    const int t = buf - 16;
    src = WU + (size_t)(t >> 1) * 2 * HH * HH + (size_t)(t & 1) * HH * HH;
    K = HH;
  }
  f16* dst = out + (size_t)buf * HH * TSTR;
  for (int idx = threadIdx.x; idx < 16 * TSTR; idx += 256) {
    const int n = rowg * 16 + idx / TSTR;
    const int k = idx % TSTR;
    const float v = (k < K) ? src[(size_t)k * HH + n] : 0.f;
    dst[(size_t)n * TSTR + k] = (f16)v;
  }
}

// ---------------------------------------------------------------------------
// MFMA node GEMM: out[M,128] = X[M,K] @ W[K,128] via mfma_f32_16x16x32_f16.
// 64-row x 128-col tile, 4 waves, wave owns 64x32 slab (acc[4][2] f32x4).
// Fragment layouts (measured m89/m91, dtype-independent):
//   A[m][k]: m=lane&15, k=8*(lane>>4)+j   B[k][n]: n=lane&15, same k
//   D[m][n]: n=lane&15, m=4*(lane>>4)+reg
// Weight staging via async global_load_lds (r6->r8: removed the serial
// stage stall; msg_k 418->196us).
// Stores go through V (f32 [64][132], aliases Wt) for coalescing.
//   MODE 1: K=128, relu(acc+bias), f32 out
//   MODE 2: K=64 encoder (X stride 64), relu(acc+bias), f32 out
//   MODE 3: K=256: chunk0=X(h), chunk1=X2(agg f32)*inv[row]; relu; f32 out
//   MODE 4: K=128 dual-output raw, out/out2 are f16* (A/B for msg gather)
// ---------------------------------------------------------------------------
template <int MODE>
__global__ __launch_bounds__(256) void gemm_mfma(
    const float* __restrict__ X, const f16* __restrict__ WT,
    const float* __restrict__ bias, float* __restrict__ out, int M,
    const float* __restrict__ X2, const float* __restrict__ inv,
    const f16* __restrict__ WT2, float* __restrict__ out2) {
  __shared__ __align__(16) char smem[17408 + 34816];
  f16* Xs = (f16*)smem;                  // [64][TSTR] f16
  f16* Wt = (f16*)(smem + 17408);        // [128][TSTR] f16
  float* V = (float*)(smem + 17408);     // [64][132] f32, aliases Wt

  const int tid = threadIdx.x;
  const int lane = tid & 63;
  const int wv = tid >> 6;
  const int l15 = lane & 15;
  const int q = lane >> 4;
  const int m0 = blockIdx.x * 64;

  f32x4 acc[4][2];
#pragma unroll
  for (int mi = 0; mi < 4; ++mi)
#pragma unroll
    for (int ni = 0; ni < 2; ++ni) {
      f32x4 z = {};
      acc[mi][ni] = z;
    }

  auto stageX = [&](const float* Xp, int stride, int KC, bool scale) {
    const int npr = KC >> 2;  // float4 per row
    for (int i = tid; i < 64 * npr; i += 256) {
      const int row = i / npr;
      const int c4 = (i - row * npr) << 2;
      float4 v = make_float4(0.f, 0.f, 0.f, 0.f);
      if (m0 + row < M) {
        v = *(const float4*)(Xp + (size_t)(m0 + row) * stride + c4);
        if (scale) {
          const float s = inv[m0 + row];
          v.x *= s; v.y *= s; v.z *= s; v.w *= s;
        }
      }
      f16x4 hv;
      hv[0] = (f16)v.x; hv[1] = (f16)v.y; hv[2] = (f16)v.z; hv[3] = (f16)v.w;
      *(f16x4*)&Xs[(size_t)row * TSTR + c4] = hv;
    }
  };

  // async 34816 B copy; completion guaranteed by the next __syncthreads()
  // (compiler drains vmcnt before s_barrier).
  auto stageW = [&](const f16* Wg) {
    const char* g = (const char*)Wg;
    char* l = (char*)Wt;
#pragma unroll
    for (int i = 0; i < 8; ++i)
      gload_lds16(g + tid * 16 + i * 4096, l + tid * 16 + i * 4096);
    if (tid < 128) gload_lds16(g + tid * 16 + 32768, l + tid * 16 + 32768);
  };

  auto mfmaN = [&](f32x4 (&ac)[4][2], int nk) {
    for (int kk = 0; kk < nk; ++kk) {
      f16x8 a[4], b[2];
#pragma unroll
      for (int mi = 0; mi < 4; ++mi)
        a[mi] = *(const f16x8*)&Xs[(size_t)(mi * 16 + l15) * TSTR + kk * 32 +
                                   q * 8];
#pragma unroll
      for (int ni = 0; ni < 2; ++ni)
        b[ni] = *(const f16x8*)&Wt[(size_t)((wv * 2 + ni) * 16 + l15) * TSTR +
                                   kk * 32 + q * 8];
#pragma unroll
      for (int mi = 0; mi < 4; ++mi)
#pragma unroll
        for (int ni = 0; ni < 2; ++ni)
          ac[mi][ni] = __builtin_amdgcn_mfma_f32_16x16x32_f16(
              a[mi], b[ni], ac[mi][ni], 0, 0, 0);
    }
  };

  auto dumpV = [&](f32x4 (&ac)[4][2], const float* bp) {
    float bv0 = 0.f, bv1 = 0.f;
    if (bp) { bv0 = bp[wv * 32 + l15]; bv1 = bp[wv * 32 + 16 + l15]; }
#pragma unroll
    for (int mi = 0; mi < 4; ++mi)
#pragma unroll
      for (int ni = 0; ni < 2; ++ni)
#pragma unroll
        for (int rr = 0; rr < 4; ++rr) {
          float v = ac[mi][ni][rr];
          if (bp) {
            v += ni ? bv1 : bv0;
            v = v > 0.f ? v : 0.f;
          }
          V[(size_t)(mi * 16 + q * 4 + rr) * 132 + wv * 32 + ni * 16 + l15] =
              v;
        }
  };

  auto storeV = [&](float* op) {
    const int tm = (tid >> 4) << 2;
    const int tn = (tid & 15) << 3;
#pragma unroll
    for (int i = 0; i < 4; ++i) {
      const int r = m0 + tm + i;
      if (r >= M) continue;
      float4* d = (float4*)(op + (size_t)r * HH + tn);
      d[0] = *(const float4*)&V[(size_t)(tm + i) * 132 + tn];
      d[1] = *(const float4*)&V[(size_t)(tm + i) * 132 + tn + 4];
    }
  };

  auto storeV16 = [&](f16* op) {  // fp16 output (MODE 4: A/B buffers)
    const int tm = (tid >> 4) << 2;
    const int tn = (tid & 15) << 3;
#pragma unroll
    for (int i = 0; i < 4; ++i) {
      const int r = m0 + tm + i;
      if (r >= M) continue;
      const float* vp = &V[(size_t)(tm + i) * 132 + tn];
      f16x8 hv;
#pragma unroll
      for (int j = 0; j < 8; ++j) hv[j] = (f16)vp[j];
      *(f16x8*)(op + (size_t)r * HH + tn) = hv;
    }
  };

  if constexpr (MODE == 2) {
    stageW(WT);                 // async; hidden under stageX
    stageX(X, 64, 64, false);
    __syncthreads();
    mfmaN(acc, 2);
    __syncthreads();   // Wt reads done; V may alias
    dumpV(acc, bias);
    __syncthreads();   // V writes visible
    storeV(out);
  } else if constexpr (MODE == 1) {
    stageW(WT);
    stageX(X, HH, 128, false);
    __syncthreads();
    mfmaN(acc, 4);
    __syncthreads();
    dumpV(acc, bias);
    __syncthreads();
    storeV(out);
  } else if constexpr (MODE == 3) {
    stageW(WT);
    stageX(X, HH, 128, false);
    __syncthreads();
    mfmaN(acc, 4);
    __syncthreads();  // all LDS reads done before restage
    stageW(WT + (size_t)HH * TSTR);   // async; hidden under stageX(X2)
    stageX(X2, HH, 128, true);
    __syncthreads();
    mfmaN(acc, 4);
    __syncthreads();
    dumpV(acc, bias);
    __syncthreads();
    storeV(out);
  } else {  // MODE 4: dual raw output, fp16 stores
    f32x4 acc2[4][2];
#pragma unroll
    for (int mi = 0; mi < 4; ++mi)
#pragma unroll
      for (int ni = 0; ni < 2; ++ni) {
        f32x4 z = {};
        acc2[mi][ni] = z;
      }
    stageW(WT);
    stageX(X, HH, 128, false);
    __syncthreads();
    mfmaN(acc, 4);
    __syncthreads();  // Wt reads done before restage
    stageW(WT2);
    __syncthreads();
    mfmaN(acc2, 4);
    __syncthreads();  // Wt reads done; V may alias
    dumpV(acc, nullptr);
    __syncthreads();  // V writes visible
    storeV16((f16*)out);
    __syncthreads();  // V reads done before overwrite
    dumpV(acc2, nullptr);
    __syncthreads();  // V writes visible
    storeV16((f16*)out2);
  }
}

// ---------------------------------------------------------------------------
// Fused message kernel via MFMA fp16 (fp32 accumulate), edges sorted by dst.
//   t = relu(ea@We0+be0); CHAIN x (t = relu(t@We_s+be_s)); P = t@WMe
//   v = relu(P + A[dst] + B[src] + bM) -> V16 f16 LDS -> segmented run
//   reduction into agg (boundary atomics + interior stores, r4-verified).
//
// r10 post-mortem: per-phase stall = the vmcnt(0) drain the compiler puts
// before s_barrier — the single-buffer schedule (mfma; barrier; stage; relu;
// barrier) gives the 34.8KB stage only the ~200cy relu window before its
// drain. Fix: DOUBLE-BUFFERED Wc, stage for phase p+1 issued BEFORE phase
// p's mfma -> the stage gets the full ~640cy MFMA window; drain at the
// post-mfma barrier is ~free. Hazard-safe: buf[(p+1)&1] = buf[(p-1)&1],
// whose reads retired two barriers earlier.
// Tile: 256 edges, 16 waves (1024 thr). Wave (wv>>2, wv&3) owns a 64-row x
// 32-col slab; per-wave code identical to r8. LDS = Tc 68K + 2xWc 68K +
// dstS = 140288 B (< 160K GROUP segment; LLVM gfx950 limit 163840).
// Epilogue V16 is f16 [256][TSTR] aliasing Tc (P via f16: ~5e-4 rel, same
// class as the rest of the f16 path).
// ---------------------------------------------------------------------------
template <int CHAIN>
__global__ __launch_bounds__(1024) void msg_k(
    const float* __restrict__ ea, const f16* __restrict__ W0T,
    const float* __restrict__ be0, const f16* __restrict__ WeT,
    const float* __restrict__ beL, const f16* __restrict__ WMeT,
    const float* __restrict__ bMl, const f16* __restrict__ A,
    const f16* __restrict__ B, const int* __restrict__ sIdx,
    const int* __restrict__ sSrc, const int* __restrict__ sDst,
    float* __restrict__ agg) {
  // LDS map: Tc [256][TSTR] f16 [0,69632) | Wc buf0 [69632,104448) |
  // Wc buf1 [104448,139264) | dstS int[256] [139264,140288).
  // V16 f16 [256][TSTR] aliases Tc after the projection.
  __shared__ __align__(16) char smem[69632 + 34816 + 34816 + 1024];
  f16* Tc = (f16*)smem;
  f16* WcB = (f16*)(smem + 69632);   // two buffers of HH*TSTR halfs
  f16* V16 = (f16*)smem;             // aliases Tc
  int* dstS = (int*)(smem + 139264);

  const int tid = threadIdx.x;
  const int lane = tid & 63;
  const int wv = tid >> 6;          // wave 0..15
  const int ew = (wv >> 2) * 64;    // edge-row offset (0/64/128/192)
  const int wn = wv & 3;            // N-column group (32 cols)
  const int l15 = lane & 15;
  const int q = lane >> 4;          // 0..3
  const int r0 = blockIdx.x * 256;  // EE % 256 == 0

  auto wptr = [&](int p) -> const f16* {
    if (p == 0) return W0T;
    if (p <= CHAIN) return WeT + (size_t)(p - 1) * HH * TSTR;
    return WMeT;
  };

  // async weight stage into buffer b: 34816 B = 2176 x16 B, 1024 threads
  auto stage_w = [&](int b, const f16* Wg) {
    const char* g = (const char*)Wg;
    char* l = (char*)(WcB + (size_t)b * HH * TSTR);
#pragma unroll
    for (int i = 0; i < 2; ++i)
      gload_lds16(g + tid * 16 + i * 16384, l + tid * 16 + i * 16384);
    if (tid < 128) gload_lds16(g + tid * 16 + 32768, l + tid * 16 + 32768);
  };

  // ---- prologue: issue W0 -> buf0; stage ea tile as fp16 into Tc ----
  stage_w(0, wptr(0));
  {
    const int xr = tid >> 2;        // edge 0..255
    const int xc = (tid & 3) << 2;  // col 0,4,8,12
    const int e = sIdx[r0 + xr];
    const float4 v = *(const float4*)(ea + (size_t)e * 16 + xc);
    f16x4 hv;
    hv[0] = (f16)v.x; hv[1] = (f16)v.y; hv[2] = (f16)v.z; hv[3] = (f16)v.w;
    *(f16x4*)&Tc[(size_t)xr * TSTR + xc] = hv;
    f16x4 z = {};
    *(f16x4*)&Tc[(size_t)xr * TSTR + 16 + xc] = z;   // K pad 16->32
    if (tid < 256) dstS[tid] = sDst[r0 + tid];
  }

  f32x4 acc[4][2];

  auto zero_acc = [&]() {
#pragma unroll
    for (int mi = 0; mi < 4; ++mi)
#pragma unroll
      for (int ni = 0; ni < 2; ++ni) {
        f32x4 z = {};
        acc[mi][ni] = z;
      }
  };

  auto mfma_steps = [&](int b, int nk) {  // nk K=32 steps from Wc buffer b
    const f16* Wc = WcB + (size_t)b * HH * TSTR;
    for (int kk = 0; kk < nk; ++kk) {
      f16x8 a[4], bb[2];
#pragma unroll
      for (int mi = 0; mi < 4; ++mi)
        a[mi] = *(const f16x8*)&Tc[(size_t)(ew + mi * 16 + l15) * TSTR +
                                   kk * 32 + q * 8];
#pragma unroll
      for (int ni = 0; ni < 2; ++ni)
        bb[ni] = *(const f16x8*)&Wc[(size_t)((wn * 2 + ni) * 16 + l15) * TSTR +
                                    kk * 32 + q * 8];
#pragma unroll
      for (int mi = 0; mi < 4; ++mi)
#pragma unroll
        for (int ni = 0; ni < 2; ++ni)
          acc[mi][ni] = __builtin_amdgcn_mfma_f32_16x16x32_f16(
              a[mi], bb[ni], acc[mi][ni], 0, 0, 0);
    }
  };

  // bias + relu + fp16-convert -> write back into Tc (caller brackets with
  // barriers).
  auto relu_body = [&](const float* bias) {
    float bv0 = bias[wn * 32 + l15];
    float bv1 = bias[wn * 32 + 16 + l15];
#pragma unroll
    for (int mi = 0; mi < 4; ++mi)
#pragma unroll
      for (int ni = 0; ni < 2; ++ni) {
        const float bb = ni ? bv1 : bv0;
#pragma unroll
        for (int rr = 0; rr < 4; ++rr) {
          float v = acc[mi][ni][rr] + bb;
          v = v > 0.f ? v : 0.f;
          Tc[(size_t)(ew + mi * 16 + q * 4 + rr) * TSTR + wn * 32 + ni * 16 +
             l15] = (f16)v;
        }
      }
  };

  // ---- phase 0 (encoder): t = relu(ea @ We0 + be0), K=32, buf0 ----
  zero_acc();
  __syncthreads();               // drains W0 gload + ea stores
  stage_w(1, wptr(1));           // next-phase weights: full mfma window
  mfma_steps(0, 1);
  __syncthreads();               // drains stage(1); buf0/Tc reads done
  relu_body(be0);
  __syncthreads();               // Tc ready

  // ---- chain phases p=s+1: use buf (s+1)&1, stage wptr(s+2)->(s+2)&1 ----
#pragma unroll
  for (int s = 0; s < CHAIN; ++s) {
    zero_acc();
    stage_w((s + 2) & 1, wptr(s + 2));   // overlaps this phase's mfma
    mfma_steps((s + 1) & 1, 4);
    __syncthreads();             // drains stage; Wc/Tc reads done
    relu_body(beL + (size_t)s * HH);
    __syncthreads();
  }

  // ---- projection: P = t @ WMe, buf (CHAIN+1)&1, no further stage ----
  zero_acc();
  mfma_steps((CHAIN + 1) & 1, 4);
  __syncthreads();  // all Tc/Wc reads retired; V16 aliases Tc

  // dump P fragments to V16 f16 [256][TSTR]
#pragma unroll
  for (int mi = 0; mi < 4; ++mi)
#pragma unroll
    for (int ni = 0; ni < 2; ++ni)
#pragma unroll
      for (int rr = 0; rr < 4; ++rr)
        V16[(size_t)(ew + mi * 16 + q * 4 + rr) * TSTR + wn * 32 + ni * 16 +
            l15] = (f16)acc[mi][ni][rr];
  __syncthreads();

  // epilogue: v = relu(P + A[dst] + B[src] + bM), in-place in V16
  const int tm = (tid >> 4) << 2;   // 0..252 (4-row groups over 256 rows)
  const int tn = (tid & 15) << 3;   // 0..120
  const float4 m0v = *(const float4*)(bMl + tn);
  const float4 m1v = *(const float4*)(bMl + tn + 4);
  const float mv[8] = {m0v.x, m0v.y, m0v.z, m0v.w,
                       m1v.x, m1v.y, m1v.z, m1v.w};
#pragma unroll
  for (int i = 0; i < 4; ++i) {
    const int rr = r0 + tm + i;
    const int d = dstS[tm + i];
    const int s = sSrc[rr];
    const f16x8 a8 = *(const f16x8*)(A + (size_t)d * HH + tn);
    const f16x8 b8 = *(const f16x8*)(B + (size_t)s * HH + tn);
    f16* vp = &V16[(size_t)(tm + i) * TSTR + tn];
    const f16x8 pv = *(const f16x8*)vp;
    f16x8 o;
#pragma unroll
    for (int j = 0; j < 8; ++j)
      o[j] = (f16)fmaxf((float)pv[j] + (float)a8[j] + (float)b8[j] + mv[j],
                        0.f);
    *(f16x8*)vp = o;   // disjoint 16B segments per thread: no race
  }
  __syncthreads();

  // segmented run reduction (r4-verified): wave-uniform 32-edge strips.
  // Interior runs own ALL edges of their dst (global sort) -> plain store;
  // first/last runs of a strip -> atomicAdd.
  const int c = tid & 127;
  const int h = tid >> 7;  // strip 0..7 (edges h*32 .. h*32+31)
  float racc = 0.f;
  int cur = dstS[h * 32];
  bool first = true;
  for (int e2 = h * 32; e2 < h * 32 + 32; ++e2) {
    const int d = dstS[e2];
    if (d != cur) {
      if (first) {
        atomicAdd(&agg[(size_t)cur * HH + c], racc);
        first = false;
      } else {
        agg[(size_t)cur * HH + c] = racc;
      }
      racc = 0.f;
      cur = d;
    }
    racc += (float)V16[(size_t)e2 * TSTR + c];
  }
  atomicAdd(&agg[(size_t)cur * HH + c], racc);
}

// ---------------------------------------------------------------------------
__global__ void count_kernel(const int* __restrict__ dst, int* cnt, int E) {
  const int i = blockIdx.x * 256 + threadIdx.x;
  if (i < E) atomicAdd(&cnt[dst[i]], 1);
}

__global__ void invcnt_kernel(const int* __restrict__ cnt, float* inv, int n) {
  const int i = blockIdx.x * 256 + threadIdx.x;
  if (i < n) inv[i] = 1.0f / (float)max(cnt[i], 1);
}

__global__ void scan_block(const int* __restrict__ cnt, int* excl, int* bsum,
                           int n) {
  __shared__ int s[256];
  const int tx = threadIdx.x;
  const int i = blockIdx.x * 256 + tx;
  const int v = (i < n) ? cnt[i] : 0;
  s[tx] = v;
  __syncthreads();
  for (int off = 1; off < 256; off <<= 1) {
    int tv = (tx >= off) ? s[tx - off] : 0;
    __syncthreads();
    s[tx] += tv;
    __syncthreads();
  }
  if (i < n) excl[i] = s[tx] - v;
  if (tx == 255) bsum[blockIdx.x] = s[255];
}

// parallel exclusive scan of the per-block sums (nb <= 512).
__global__ __launch_bounds__(512) void scan_bsum(int* bsum, int nb) {
  __shared__ int s[512];
  const int t = threadIdx.x;
  const int v0 = (t < nb) ? bsum[t] : 0;
  s[t] = v0;
  __syncthreads();
  for (int off = 1; off < 512; off <<= 1) {
    const int tv = (t >= off) ? s[t - off] : 0;
    __syncthreads();
    s[t] += tv;
    __syncthreads();
  }
  if (t < nb) bsum[t] = s[t] - v0;  // exclusive
}

__global__ void scan_add(int* excl, const int* __restrict__ bsum, int n) {
  const int i = blockIdx.x * 256 + threadIdx.x;
  if (i < n) excl[i] += bsum[blockIdx.x];
}

__global__ void scatter_edges(const int* __restrict__ dst,
                              const int* __restrict__ src,
                              const int* __restrict__ off, int* ctr, int* sIdx,
                              int* sSrc, int* sDst, int E) {
  const int e = blockIdx.x * 256 + threadIdx.x;
  if (e >= E) return;
  const int d = dst[e];
  const int p = off[d] + atomicAdd(&ctr[d], 1);
  sIdx[p] = e;
  sSrc[p] = src[e];
  sDst[p] = d;
}

__global__ void pool_accum(const float* __restrict__ h,
                           const int* __restrict__ batch,
                           float* __restrict__ gsum, int M) {
  const int col = threadIdx.x;
  const int r0 = blockIdx.x * 64;
  const int rend = min(r0 + 64, M);
  if (r0 >= M) return;
  float acc = 0.f;
  int cur = batch[r0];
  for (int r = r0; r < rend; ++r) {
    const int b = batch[r];
    if (b != cur) {
      atomicAdd(&gsum[(size_t)cur * HH + col], acc);
      acc = 0.f;
      cur = b;
    }
    acc += h[(size_t)r * HH + col];
  }
  atomicAdd(&gsum[(size_t)cur * HH + col], acc);
}

__global__ void gcnt_kernel(const int* __restrict__ batch, int* gcnt, int n) {
  const int i = blockIdx.x * 256 + threadIdx.x;
  if (i < n) atomicAdd(&gcnt[batch[i]], 1);
}

__global__ void head_kernel(const float* __restrict__ gsum,
                            const int* __restrict__ gcnt,
                            const float* __restrict__ Wh,
                            const float* __restrict__ bh,
                            float* __restrict__ out) {
  const int g = blockIdx.x;
  const int t = threadIdx.x;  // 128 threads
  float v = gsum[(size_t)g * HH + t] * Wh[t];
#pragma unroll
  for (int o = 32; o > 0; o >>= 1) v += __shfl_down(v, o, 64);
  __shared__ float red[2];
  if ((t & 63) == 0) red[t >> 6] = v;
  __syncthreads();
  if (t == 0) {
    const float s = red[0] + red[1];
    const float c = (float)max(gcnt[g], 1);
    out[g] = s / c + bh[0];
  }
}

// ---------------------------------------------------------------------------
extern "C" void kernel_launch(void* const* d_in, const int* in_sizes, int n_in,
                              void* d_out, int out_size, void* d_ws,
                              size_t ws_size, hipStream_t stream) {
  (void)in_sizes; (void)n_in; (void)out_size;
  const float* x = (const float*)d_in[0];
  const int* ei = (const int*)d_in[1];
  const float* ea = (const float*)d_in[2];
  const int* batch = (const int*)d_in[3];
  const float* Wn0 = (const float*)d_in[4];
  const float* bn0 = (const float*)d_in[5];
  const float* We0 = (const float*)d_in[6];
  const float* be0 = (const float*)d_in[7];
  const float* WM = (const float*)d_in[8];
  const float* bM = (const float*)d_in[9];
  const float* WU = (const float*)d_in[10];
  const float* bU = (const float*)d_in[11];
  const float* Wn = (const float*)d_in[12];
  const float* bn = (const float*)d_in[13];
  const float* We = (const float*)d_in[14];
  const float* be = (const float*)d_in[15];
  const float* Wh = (const float*)d_in[16];
  const float* bh = (const float*)d_in[17];

  const int* srcI = ei;       // edge_index[0]
  const int* dstI = ei + EE;  // edge_index[1]

  // workspace carve — ~166 MB (r4-verified layout)
  float* w = (float*)d_ws;
  size_t o = 0;
  float* h = w + o;    o += (size_t)NN * HH;
  float* agg = w + o;  o += (size_t)NN * HH;
  f16* A16 = (f16*)(w + o); o += (size_t)NN * HH / 2;
  f16* B16 = (f16*)(w + o); o += (size_t)NN * HH / 2;
  float* gsum = w + o; o += (size_t)GG * HH;
  float* invc = w + o; o += (size_t)NN;
  int* cnt = (int*)(w + o);  o += (size_t)NN;
  int* gcnt = (int*)(w + o); o += (size_t)GG;
  int* off = (int*)(w + o);  o += (size_t)NN;
  int* ctr = (int*)(w + o);  o += (size_t)NN;
  int* bsum = (int*)(w + o); o += 512;
  int* sIdx = (int*)(w + o); o += (size_t)EE;
  int* sSrc = (int*)(w + o); o += (size_t)EE;
  int* sDst = (int*)(w + o); o += (size_t)EE;
  f16* Wp = (f16*)(w + o);   o += (size_t)22 * HH * TSTR / 2;
  if (o * sizeof(float) > ws_size) return;  // clean diagnosable failure

  auto WB = [&](int i) { return Wp + (size_t)i * HH * TSTR; };

  const dim3 blk(256);
  const int gridN = (NN + BM - 1) / BM;   // 1563
  const int gridE = EE / 256;             // 2500 (256 edges/block)
  const int NBLK = (NN + 255) / 256;      // 391

  hipMemsetAsync(cnt, 0, (size_t)NN * sizeof(int), stream);
  hipMemsetAsync(ctr, 0, (size_t)NN * sizeof(int), stream);
  hipMemsetAsync(gsum, 0, (size_t)GG * HH * sizeof(float), stream);
  hipMemsetAsync(gcnt, 0, (size_t)GG * sizeof(int), stream);

  count_kernel<<<(EE + 255) / 256, blk, 0, stream>>>(dstI, cnt, EE);
  scan_block<<<NBLK, blk, 0, stream>>>(cnt, off, bsum, NN);
  scan_bsum<<<1, dim3(512), 0, stream>>>(bsum, NBLK);
  scan_add<<<NBLK, blk, 0, stream>>>(off, bsum, NN);
  scatter_edges<<<(EE + 255) / 256, blk, 0, stream>>>(dstI, srcI, off, ctr,
                                                      sIdx, sSrc, sDst, EE);
  invcnt_kernel<<<(NN + 255) / 256, blk, 0, stream>>>(cnt, invc, NN);
  prep_w<<<22 * 8, blk, 0, stream>>>(We0, We, WM, Wn0, Wn, WU, Wp);

  // node encoder: h = relu(x @ Wn0 + bn0)   [MFMA, K=64]
  gemm_mfma<2><<<gridN, blk, 0, stream>>>(x, WB(6), bn0, h, NN, nullptr,
                                          nullptr, nullptr, nullptr);

  for (int l = 0; l < LL; ++l) {
    // fused A/B projections (fp16 out): A = h@WM1 (dst), B = h@WM2 (src)
    gemm_mfma<4><<<gridN, blk, 0, stream>>>(h, WB(7 + l), nullptr,
                                            (float*)A16, NN, nullptr, nullptr,
                                            WB(10 + l), (float*)B16);
    hipMemsetAsync(agg, 0, (size_t)NN * HH * sizeof(float), stream);
    switch (l) {
      case 0:
        msg_k<0><<<gridE, dim3(1024), 0, stream>>>(
            ea, WB(0), be0, WB(1), be, WB(3), bM + 0 * HH, A16, B16, sIdx,
            sSrc, sDst, agg);
        break;
      case 1:
        msg_k<1><<<gridE, dim3(1024), 0, stream>>>(
            ea, WB(0), be0, WB(1), be, WB(4), bM + 1 * HH, A16, B16, sIdx,
            sSrc, sDst, agg);
        break;
      default:
        msg_k<2><<<gridE, dim3(1024), 0, stream>>>(
            ea, WB(0), be0, WB(1), be, WB(5), bM + 2 * HH, A16, B16, sIdx,
            sSrc, sDst, agg);
        break;
    }
    // update: h = relu([h, agg/cnt] @ WU + bU)   [MFMA, K=256 two-chunk]
    gemm_mfma<3><<<gridN, blk, 0, stream>>>(h, WB(16 + 2 * l), bU + l * HH, h,
                                            NN, agg, invc, nullptr, nullptr);
    // node linear: h = relu(h @ Wn + bn)
    gemm_mfma<1><<<gridN, blk, 0, stream>>>(h, WB(13 + l), bn + l * HH, h, NN,
                                            nullptr, nullptr, nullptr,
                                            nullptr);
  }

  pool_accum<<<gridN, dim3(128), 0, stream>>>(h, batch, gsum, NN);
  gcnt_kernel<<<(NN + 255) / 256, blk, 0, stream>>>(batch, gcnt, NN);
  head_kernel<<<GG, dim3(128), 0, stream>>>(gsum, gcnt, Wh, bh, (float*)d_out);
}

// Round 12
// 1035.184 us; speedup vs baseline: 1.1074x; 1.1074x over previous
//
#include <hip/hip_runtime.h>

#define NN 100000
#define EE 640000
#define GG 256
#define LL 3
#define HH 128

constexpr int BM = 64;   // rows per block (node gemms)
constexpr int BK = 16;   // k-chunk (fp32 gemm, legacy)

typedef _Float16 f16;
typedef f16 f16x8 __attribute__((ext_vector_type(8)));
typedef f16 f16x4 __attribute__((ext_vector_type(4)));
typedef f16 f16x2 __attribute__((ext_vector_type(2)));
typedef float f32x4 __attribute__((ext_vector_type(4)));

// padded row stride (halfs) for transposed weight / activation tiles.
// 136 halfs = 272 B = 68 words; 68 % 32 = 4 -> fragment rows land 4 banks
// apart; a wave's b128 fragment read hits the 8-words/bank optimum.
#define TSTR 136

// async global->LDS, 16 B per lane (gfx950). Dest must be linear in lane
// order: HW uses wave-uniform base + lane*16 (m104). Our staging is a
// straight contiguous copy, so per-lane dst = base + tid*16 is exactly that.
__device__ __forceinline__ void gload_lds16(const void* g, void* l) {
  __builtin_amdgcn_global_load_lds(
      (const __attribute__((address_space(1))) void*)g,
      (__attribute__((address_space(3))) void*)l, 16, 0, 0);
}

// ---------------------------------------------------------------------------
// LEGACY fp32 tiled GEMM (verified in the 2897us kernel). Kept uninstantiated
// as a revert path for bisection; costs nothing when unused.
// ---------------------------------------------------------------------------
template <int MODE>
__global__ __launch_bounds__(256) void gemm_k(
    const float* __restrict__ X, const float* __restrict__ W,
    const float* __restrict__ bias, float* __restrict__ out, int M, int K,
    const float* __restrict__ X2, const float* __restrict__ inv) {
  __shared__ __align__(16) float Xs[BK][BM];
  __shared__ __align__(16) float Ws[BK][HH];

  const int tid = threadIdx.x;
  const int m0 = blockIdx.x * BM;
  const int tm = (tid >> 4) << 2;
  const int tn = (tid & 15) << 3;
  const int xr = tid >> 2;
  const int xc = (tid & 3) << 2;

  float acc[4][8];
#pragma unroll
  for (int i = 0; i < 4; ++i)
#pragma unroll
    for (int j = 0; j < 8; ++j) acc[i][j] = 0.f;

  for (int k0 = 0; k0 < K; k0 += BK) {
    float4 xv = make_float4(0.f, 0.f, 0.f, 0.f);
    if (m0 + xr < M) {
      if (MODE == 3) {
        if (k0 < HH) {
          xv = *(const float4*)(X + (size_t)(m0 + xr) * HH + k0 + xc);
        } else {
          xv = *(const float4*)(X2 + (size_t)(m0 + xr) * HH + (k0 - HH) + xc);
          const float s = inv[m0 + xr];
          xv.x *= s; xv.y *= s; xv.z *= s; xv.w *= s;
        }
      } else {
        xv = *(const float4*)(X + (size_t)(m0 + xr) * K + k0 + xc);
      }
    }
    Xs[xc + 0][xr] = xv.x;
    Xs[xc + 1][xr] = xv.y;
    Xs[xc + 2][xr] = xv.z;
    Xs[xc + 3][xr] = xv.w;
#pragma unroll
    for (int i = 0; i < 2; ++i) {
      const int q = tid + i * 256;
      const int row = q >> 5;
      const int c4 = (q & 31) << 2;
      *(float4*)&Ws[row][c4] =
          *(const float4*)(W + (size_t)(k0 + row) * HH + c4);
    }
    __syncthreads();
#pragma unroll
    for (int k = 0; k < BK; ++k) {
      const float4 x4 = *(const float4*)&Xs[k][tm];
      const float4 w0 = *(const float4*)&Ws[k][tn];
      const float4 w1 = *(const float4*)&Ws[k][tn + 4];
      const float xr_[4] = {x4.x, x4.y, x4.z, x4.w};
      const float wr_[8] = {w0.x, w0.y, w0.z, w0.w, w1.x, w1.y, w1.z, w1.w};
#pragma unroll
      for (int i = 0; i < 4; ++i)
#pragma unroll
        for (int j = 0; j < 8; ++j)
          acc[i][j] = fmaf(xr_[i], wr_[j], acc[i][j]);
    }
    __syncthreads();
  }

#pragma unroll
  for (int i = 0; i < 4; ++i) {
    const int r = m0 + tm + i;
    if (r >= M) continue;
    float o[8];
#pragma unroll
    for (int j = 0; j < 8; ++j) {
      float v = acc[i][j];
      if (MODE == 1 || MODE == 3) {
        v += bias[tn + j];
        v = v > 0.f ? v : 0.f;
      }
      o[j] = v;
    }
    float4* d4 = (float4*)(out + (size_t)r * HH + tn);
    d4[0] = make_float4(o[0], o[1], o[2], o[3]);
    d4[1] = make_float4(o[4], o[5], o[6], o[7]);
  }
}

// ---------------------------------------------------------------------------
// Weight prep: transpose + fp16-convert + zero-pad ALL weights once into a
// 22-buffer arena of [128 n][TSTR k] halfs (single launch):
//   0:      We0^T          (K=16, msg encoder; k>=16 zero -> K=32 pad works)
//   1..2:   We[l]^T        l=0,1 (msg chain layers)
//   3..5:   WMe[l]^T       = (WM[l] + 2*H*H)^T, l=0..2 (msg projection)
//   6:      Wn0^T          (K=64, node encoder)
//   7..9:   WM1[l]^T       (A projection, dst), l=0..2
//   10..12: WM2[l]^T       (B projection, src)
//   13..15: Wn[l]^T
//   16..21: WU[l]^T        chunks: 16+2l = rows 0..127 (h part),
//                          17+2l = rows 128..255 (agg part)
// ---------------------------------------------------------------------------
__global__ void prep_w(const float* __restrict__ We0,
                       const float* __restrict__ We,
                       const float* __restrict__ WM,
                       const float* __restrict__ Wn0,
                       const float* __restrict__ Wn,
                       const float* __restrict__ WU, f16* __restrict__ out) {
  const int buf = blockIdx.x >> 3;
  const int rowg = blockIdx.x & 7;  // 16 n-rows per block
  const float* src;
  int K;
  if (buf == 0) {
    src = We0; K = 16;
  } else if (buf <= 2) {
    src = We + (size_t)(buf - 1) * HH * HH; K = HH;
  } else if (buf <= 5) {
    src = WM + (size_t)(buf - 3) * 3 * HH * HH + 2 * HH * HH; K = HH;
  } else if (buf == 6) {
    src = Wn0; K = 64;
  } else if (buf <= 9) {
    src = WM + (size_t)(buf - 7) * 3 * HH * HH; K = HH;
  } else if (buf <= 12) {
    src = WM + (size_t)(buf - 10) * 3 * HH * HH + HH * HH; K = HH;
  } else if (buf <= 15) {
    src = Wn + (size_t)(buf - 13) * HH * HH; K = HH;
  } else {
    const int t = buf - 16;
    src = WU + (size_t)(t >> 1) * 2 * HH * HH + (size_t)(t & 1) * HH * HH;
    K = HH;
  }
  f16* dst = out + (size_t)buf * HH * TSTR;
  for (int idx = threadIdx.x; idx < 16 * TSTR; idx += 256) {
    const int n = rowg * 16 + idx / TSTR;
    const int k = idx % TSTR;
    const float v = (k < K) ? src[(size_t)k * HH + n] : 0.f;
    dst[(size_t)n * TSTR + k] = (f16)v;
  }
}

// ---------------------------------------------------------------------------
// MFMA node GEMM: out[M,128] = X[M,K] @ W[K,128] via mfma_f32_16x16x32_f16.
// 64-row x 128-col tile, 4 waves, wave owns 64x32 slab (acc[4][2] f32x4).
// Fragment layouts (measured m89/m91, dtype-independent):
//   A[m][k]: m=lane&15, k=8*(lane>>4)+j   B[k][n]: n=lane&15, same k
//   D[m][n]: n=lane&15, m=4*(lane>>4)+reg
// Weight staging via async global_load_lds (r6->r8: removed the serial
// stage stall; msg_k 418->196us).
// r11->r12: h stored as f16 end-to-end (node-path traffic halves; the store
// rounds exactly where the stage-convert used to -> numerics unchanged).
// Stores go through V (f32 [64][132], aliases Wt) for coalescing.
//   MODE 1: K=128, X f16 (h), relu(acc+bias), f16 out
//   MODE 2: K=64 encoder, X f32 (x, stride 64), relu(acc+bias), f16 out
//   MODE 3: K=256: chunk0=X f16 (h), chunk1=X2 f32 (agg)*inv[row];
//           relu(acc+bias), f16 out (in-place h: block-local rows only)
//   MODE 4: K=128 dual-output raw, X f16 (h), out/out2 f16 (A/B buffers)
// ---------------------------------------------------------------------------
template <int MODE>
__global__ __launch_bounds__(256) void gemm_mfma(
    const float* __restrict__ X, const f16* __restrict__ WT,
    const float* __restrict__ bias, float* __restrict__ out, int M,
    const float* __restrict__ X2, const float* __restrict__ inv,
    const f16* __restrict__ WT2, float* __restrict__ out2) {
  __shared__ __align__(16) char smem[17408 + 34816];
  f16* Xs = (f16*)smem;                  // [64][TSTR] f16
  f16* Wt = (f16*)(smem + 17408);        // [128][TSTR] f16
  float* V = (float*)(smem + 17408);     // [64][132] f32, aliases Wt

  const int tid = threadIdx.x;
  const int lane = tid & 63;
  const int wv = tid >> 6;
  const int l15 = lane & 15;
  const int q = lane >> 4;
  const int m0 = blockIdx.x * 64;

  f32x4 acc[4][2];
#pragma unroll
  for (int mi = 0; mi < 4; ++mi)
#pragma unroll
    for (int ni = 0; ni < 2; ++ni) {
      f32x4 z = {};
      acc[mi][ni] = z;
    }

  auto stageX = [&](const float* Xp, int stride, int KC, bool scale) {
    const int npr = KC >> 2;  // float4 per row
    for (int i = tid; i < 64 * npr; i += 256) {
      const int row = i / npr;
      const int c4 = (i - row * npr) << 2;
      float4 v = make_float4(0.f, 0.f, 0.f, 0.f);
      if (m0 + row < M) {
        v = *(const float4*)(Xp + (size_t)(m0 + row) * stride + c4);
        if (scale) {
          const float s = inv[m0 + row];
          v.x *= s; v.y *= s; v.z *= s; v.w *= s;
        }
      }
      f16x4 hv;
      hv[0] = (f16)v.x; hv[1] = (f16)v.y; hv[2] = (f16)v.z; hv[3] = (f16)v.w;
      *(f16x4*)&Xs[(size_t)row * TSTR + c4] = hv;
    }
  };

  auto stageX16 = [&](const f16* Xp) {  // 64 rows x 128 halfs, contiguous
    for (int i = tid; i < 1024; i += 256) {
      const int row = i >> 4;
      const int c8 = (i & 15) << 3;
      f16x8 v = {};
      if (m0 + row < M) v = *(const f16x8*)(Xp + (size_t)(m0 + row) * HH + c8);
      *(f16x8*)&Xs[(size_t)row * TSTR + c8] = v;
    }
  };

  // async 34816 B copy; completion guaranteed by the next __syncthreads()
  // (compiler drains vmcnt before s_barrier).
  auto stageW = [&](const f16* Wg) {
    const char* g = (const char*)Wg;
    char* l = (char*)Wt;
#pragma unroll
    for (int i = 0; i < 8; ++i)
      gload_lds16(g + tid * 16 + i * 4096, l + tid * 16 + i * 4096);
    if (tid < 128) gload_lds16(g + tid * 16 + 32768, l + tid * 16 + 32768);
  };

  auto mfmaN = [&](f32x4 (&ac)[4][2], int nk) {
    for (int kk = 0; kk < nk; ++kk) {
      f16x8 a[4], b[2];
#pragma unroll
      for (int mi = 0; mi < 4; ++mi)
        a[mi] = *(const f16x8*)&Xs[(size_t)(mi * 16 + l15) * TSTR + kk * 32 +
                                   q * 8];
#pragma unroll
      for (int ni = 0; ni < 2; ++ni)
        b[ni] = *(const f16x8*)&Wt[(size_t)((wv * 2 + ni) * 16 + l15) * TSTR +
                                   kk * 32 + q * 8];
#pragma unroll
      for (int mi = 0; mi < 4; ++mi)
#pragma unroll
        for (int ni = 0; ni < 2; ++ni)
          ac[mi][ni] = __builtin_amdgcn_mfma_f32_16x16x32_f16(
              a[mi], b[ni], ac[mi][ni], 0, 0, 0);
    }
  };

  auto dumpV = [&](f32x4 (&ac)[4][2], const float* bp) {
    float bv0 = 0.f, bv1 = 0.f;
    if (bp) { bv0 = bp[wv * 32 + l15]; bv1 = bp[wv * 32 + 16 + l15]; }
#pragma unroll
    for (int mi = 0; mi < 4; ++mi)
#pragma unroll
      for (int ni = 0; ni < 2; ++ni)
#pragma unroll
        for (int rr = 0; rr < 4; ++rr) {
          float v = ac[mi][ni][rr];
          if (bp) {
            v += ni ? bv1 : bv0;
            v = v > 0.f ? v : 0.f;
          }
          V[(size_t)(mi * 16 + q * 4 + rr) * 132 + wv * 32 + ni * 16 + l15] =
              v;
        }
  };

  auto storeV16 = [&](f16* op) {  // fp16 output (coalesced f16x8 per thread)
    const int tm = (tid >> 4) << 2;
    const int tn = (tid & 15) << 3;
#pragma unroll
    for (int i = 0; i < 4; ++i) {
      const int r = m0 + tm + i;
      if (r >= M) continue;
      const float* vp = &V[(size_t)(tm + i) * 132 + tn];
      f16x8 hv;
#pragma unroll
      for (int j = 0; j < 8; ++j) hv[j] = (f16)vp[j];
      *(f16x8*)(op + (size_t)r * HH + tn) = hv;
    }
  };

  if constexpr (MODE == 2) {
    stageW(WT);                 // async; hidden under stageX
    stageX(X, 64, 64, false);   // x is f32
    __syncthreads();
    mfmaN(acc, 2);
    __syncthreads();   // Wt reads done; V may alias
    dumpV(acc, bias);
    __syncthreads();   // V writes visible
    storeV16((f16*)out);
  } else if constexpr (MODE == 1) {
    stageW(WT);
    stageX16((const f16*)X);
    __syncthreads();
    mfmaN(acc, 4);
    __syncthreads();
    dumpV(acc, bias);
    __syncthreads();
    storeV16((f16*)out);
  } else if constexpr (MODE == 3) {
    stageW(WT);
    stageX16((const f16*)X);    // h chunk (f16)
    __syncthreads();
    mfmaN(acc, 4);
    __syncthreads();  // all LDS reads done before restage
    stageW(WT + (size_t)HH * TSTR);   // async; hidden under stageX(agg)
    stageX(X2, HH, 128, true);        // agg chunk (f32, inv-scaled)
    __syncthreads();
    mfmaN(acc, 4);
    __syncthreads();
    dumpV(acc, bias);
    __syncthreads();
    storeV16((f16*)out);
  } else {  // MODE 4: dual raw output, fp16 stores
    f32x4 acc2[4][2];
#pragma unroll
    for (int mi = 0; mi < 4; ++mi)
#pragma unroll
      for (int ni = 0; ni < 2; ++ni) {
        f32x4 z = {};
        acc2[mi][ni] = z;
      }
    stageW(WT);
    stageX16((const f16*)X);
    __syncthreads();
    mfmaN(acc, 4);
    __syncthreads();  // Wt reads done before restage
    stageW(WT2);
    __syncthreads();
    mfmaN(acc2, 4);
    __syncthreads();  // Wt reads done; V may alias
    dumpV(acc, nullptr);
    __syncthreads();  // V writes visible
    storeV16((f16*)out);
    __syncthreads();  // V reads done before overwrite
    dumpV(acc2, nullptr);
    __syncthreads();  // V writes visible
    storeV16((f16*)out2);
  }
}

// ---------------------------------------------------------------------------
// Fused message kernel via MFMA fp16 (fp32 accumulate), edges sorted by dst.
//   t = relu(ea@We0+be0); CHAIN x (t = relu(t@We_s+be_s)); P = t@WMe
//   v = relu(P + A[dst] + B[src] + bM) -> V f32 LDS -> segmented run
//   reduction into agg (boundary atomics + interior stores, r4-verified).
// r10 config (measured 179us/dispatch, best of r8/r10/r11 variants):
// 128 edges/block, 8 waves (512 thr), single-buffered Wc staged via async
// global_load_lds right after the barrier that retires the prior phase's Wc
// reads. r11's dbuf+256-edge variant was within noise (183) -> reverted.
// Residual ~180us is LDS-read + VALU co-bound (r11 analysis); parked.
// ---------------------------------------------------------------------------
template <int CHAIN>
__global__ __launch_bounds__(512) void msg_k(
    const float* __restrict__ ea, const f16* __restrict__ W0T,
    const float* __restrict__ be0, const f16* __restrict__ WeT,
    const float* __restrict__ beL, const f16* __restrict__ WMeT,
    const float* __restrict__ bMl, const f16* __restrict__ A,
    const f16* __restrict__ B, const int* __restrict__ sIdx,
    const int* __restrict__ sSrc, const int* __restrict__ sDst,
    float* __restrict__ agg) {
  // LDS: Tc [128][TSTR] f16 (34816 B) | Wc [128][TSTR] f16 (34816 B) |
  // dstS int[128] (512 B). Epilogue V [128][129] f32 = 66048 B aliases
  // Tc+Wc (both dead after the projection MFMA); dstS sits above V.
  __shared__ __align__(16) char smem[34816 + 34816 + 512];
  f16* Tc = (f16*)smem;
  f16* Wc = (f16*)(smem + 34816);
  float* V = (float*)smem;  // [128][129] f32, aliases Tc+Wc
  int* dstS = (int*)(smem + 69632);

  const int tid = threadIdx.x;
  const int lane = tid & 63;
  const int wv = tid >> 6;        // wave 0..7
  const int ew = (wv >> 2) * 64;  // edge-row offset of this wave's half
  const int wn = wv & 3;          // N-column group (32 cols)
  const int l15 = lane & 15;
  const int q = lane >> 4;        // 0..3
  const int r0 = blockIdx.x * 128;  // EE % 128 == 0

  auto wptr = [&](int p) -> const f16* {
    if (p == 0) return W0T;
    if (p <= CHAIN) return WeT + (size_t)(p - 1) * HH * TSTR;
    return WMeT;
  };

  // async weight stage: 34816 B = 2176 float4 via global_load_lds width-16
  auto stage_w = [&](const f16* Wg) {
    const char* g = (const char*)Wg;
    char* l = (char*)Wc;
#pragma unroll
    for (int i = 0; i < 4; ++i)
      gload_lds16(g + tid * 16 + i * 8192, l + tid * 16 + i * 8192);
    if (tid < 128) gload_lds16(g + tid * 16 + 32768, l + tid * 16 + 32768);
  };

  // ---- prologue: issue W0 async; stage ea tile as fp16 into Tc ----
  stage_w(wptr(0));
  {
    const int xr = tid >> 2;        // edge 0..127
    const int xc = (tid & 3) << 2;  // col 0,4,8,12
    const int e = sIdx[r0 + xr];
    const float4 v = *(const float4*)(ea + (size_t)e * 16 + xc);
    f16x4 hv;
    hv[0] = (f16)v.x; hv[1] = (f16)v.y; hv[2] = (f16)v.z; hv[3] = (f16)v.w;
    *(f16x4*)&Tc[(size_t)xr * TSTR + xc] = hv;
    f16x4 z = {};
    *(f16x4*)&Tc[(size_t)xr * TSTR + 16 + xc] = z;
    if (tid < 128) dstS[tid] = sDst[r0 + tid];
  }

  f32x4 acc[4][2];

  auto zero_acc = [&]() {
#pragma unroll
    for (int mi = 0; mi < 4; ++mi)
#pragma unroll
      for (int ni = 0; ni < 2; ++ni) {
        f32x4 z = {};
        acc[mi][ni] = z;
      }
  };

  auto mfma_steps = [&](int nk) {  // nk K=32 steps
    for (int kk = 0; kk < nk; ++kk) {
      f16x8 a[4], b[2];
#pragma unroll
      for (int mi = 0; mi < 4; ++mi)
        a[mi] = *(const f16x8*)&Tc[(size_t)(ew + mi * 16 + l15) * TSTR +
                                   kk * 32 + q * 8];
#pragma unroll
      for (int ni = 0; ni < 2; ++ni)
        b[ni] = *(const f16x8*)&Wc[(size_t)((wn * 2 + ni) * 16 + l15) * TSTR +
                                   kk * 32 + q * 8];
#pragma unroll
      for (int mi = 0; mi < 4; ++mi)
#pragma unroll
        for (int ni = 0; ni < 2; ++ni)
          acc[mi][ni] = __builtin_amdgcn_mfma_f32_16x16x32_f16(
              a[mi], b[ni], acc[mi][ni], 0, 0, 0);
    }
  };

  // bias + relu + fp16-convert -> write back into Tc (NO internal barrier;
  // caller brackets with barriers). Runs while the async W stage is in
  // flight, hiding its L2 latency.
  auto relu_body = [&](const float* bias) {
    float bv0 = bias[wn * 32 + l15];
    float bv1 = bias[wn * 32 + 16 + l15];
#pragma unroll
    for (int mi = 0; mi < 4; ++mi)
#pragma unroll
      for (int ni = 0; ni < 2; ++ni) {
        const float bb = ni ? bv1 : bv0;
#pragma unroll
        for (int rr = 0; rr < 4; ++rr) {
          float v = acc[mi][ni][rr] + bb;
          v = v > 0.f ? v : 0.f;
          Tc[(size_t)(ew + mi * 16 + q * 4 + rr) * TSTR + wn * 32 + ni * 16 +
             l15] = (f16)v;
        }
      }
  };

  // ---- phase 0 (encoder): t = relu(ea @ We0 + be0), K=32 zero-padded ----
  zero_acc();
  __syncthreads();               // drains W0 gload + ea stores
  mfma_steps(1);
  __syncthreads();               // Wc reads done
  stage_w(wptr(1));              // async next-phase weights
  relu_body(be0);                // overlaps the loads
  __syncthreads();               // drains; Tc + Wc ready

  // ---- chain: t = relu(t @ We_s + be_s), K=128 ----
#pragma unroll
  for (int s = 0; s < CHAIN; ++s) {
    zero_acc();
    mfma_steps(4);
    __syncthreads();             // Wc/Tc reads done
    stage_w(wptr(s + 2));        // s+2 <= CHAIN+1 = projection
    relu_body(beL + (size_t)s * HH);
    __syncthreads();
  }

  // ---- projection: P = t @ WMe, K=128 ----
  zero_acc();
  mfma_steps(4);
  __syncthreads();  // Wc/Tc reads done; no gloads outstanding; V aliases

  // dump P fragments to V [128][129] f32 (D-layout -> row layout)
#pragma unroll
  for (int mi = 0; mi < 4; ++mi)
#pragma unroll
    for (int ni = 0; ni < 2; ++ni)
#pragma unroll
      for (int rr = 0; rr < 4; ++rr)
        V[(size_t)(ew + mi * 16 + q * 4 + rr) * 129 + wn * 32 + ni * 16 +
          l15] = acc[mi][ni][rr];
  __syncthreads();

  // epilogue: v = relu(P + A[dst] + B[src] + bM), in-place in V (A/B fp16)
  const int tm = (tid >> 4) << 2;   // 0..124 (4-row groups over 128 rows)
  const int tn = (tid & 15) << 3;   // 0..120
  const float4 m0v = *(const float4*)(bMl + tn);
  const float4 m1v = *(const float4*)(bMl + tn + 4);
  const float mv[8] = {m0v.x, m0v.y, m0v.z, m0v.w,
                       m1v.x, m1v.y, m1v.z, m1v.w};
#pragma unroll
  for (int i = 0; i < 4; ++i) {
    const int rr = r0 + tm + i;
    const int d = dstS[tm + i];
    const int s = sSrc[rr];
    const f16x8 a8 = *(const f16x8*)(A + (size_t)d * HH + tn);
    const f16x8 b8 = *(const f16x8*)(B + (size_t)s * HH + tn);
    float* vp = &V[(size_t)(tm + i) * 129 + tn];
#pragma unroll
    for (int j = 0; j < 8; ++j)
      vp[j] = fmaxf(vp[j] + (float)a8[j] + (float)b8[j] + mv[j], 0.f);
  }
  __syncthreads();

  // segmented run reduction (r4-verified): wave-uniform 32-edge strips.
  // Interior runs own ALL edges of their dst (global sort) -> plain store;
  // first/last runs of a strip -> atomicAdd.
  const int c = tid & 127;
  const int h = tid >> 7;  // strip 0..3 (edges h*32 .. h*32+31)
  float racc = 0.f;
  int cur = dstS[h * 32];
  bool first = true;
  for (int e2 = h * 32; e2 < h * 32 + 32; ++e2) {
    const int d = dstS[e2];
    if (d != cur) {
      if (first) {
        atomicAdd(&agg[(size_t)cur * HH + c], racc);
        first = false;
      } else {
        agg[(size_t)cur * HH + c] = racc;
      }
      racc = 0.f;
      cur = d;
    }
    racc += V[(size_t)e2 * 129 + c];
  }
  atomicAdd(&agg[(size_t)cur * HH + c], racc);
}

// ---------------------------------------------------------------------------
__global__ void count_kernel(const int* __restrict__ dst, int* cnt, int E) {
  const int i = blockIdx.x * 256 + threadIdx.x;
  if (i < E) atomicAdd(&cnt[dst[i]], 1);
}

__global__ void invcnt_kernel(const int* __restrict__ cnt, float* inv, int n) {
  const int i = blockIdx.x * 256 + threadIdx.x;
  if (i < n) inv[i] = 1.0f / (float)max(cnt[i], 1);
}

__global__ void scan_block(const int* __restrict__ cnt, int* excl, int* bsum,
                           int n) {
  __shared__ int s[256];
  const int tx = threadIdx.x;
  const int i = blockIdx.x * 256 + tx;
  const int v = (i < n) ? cnt[i] : 0;
  s[tx] = v;
  __syncthreads();
  for (int off = 1; off < 256; off <<= 1) {
    int tv = (tx >= off) ? s[tx - off] : 0;
    __syncthreads();
    s[tx] += tv;
    __syncthreads();
  }
  if (i < n) excl[i] = s[tx] - v;
  if (tx == 255) bsum[blockIdx.x] = s[255];
}

// parallel exclusive scan of the per-block sums (nb <= 512).
__global__ __launch_bounds__(512) void scan_bsum(int* bsum, int nb) {
  __shared__ int s[512];
  const int t = threadIdx.x;
  const int v0 = (t < nb) ? bsum[t] : 0;
  s[t] = v0;
  __syncthreads();
  for (int off = 1; off < 512; off <<= 1) {
    const int tv = (t >= off) ? s[t - off] : 0;
    __syncthreads();
    s[t] += tv;
    __syncthreads();
  }
  if (t < nb) bsum[t] = s[t] - v0;  // exclusive
}

__global__ void scan_add(int* excl, const int* __restrict__ bsum, int n) {
  const int i = blockIdx.x * 256 + threadIdx.x;
  if (i < n) excl[i] += bsum[blockIdx.x];
}

__global__ void scatter_edges(const int* __restrict__ dst,
                              const int* __restrict__ src,
                              const int* __restrict__ off, int* ctr, int* sIdx,
                              int* sSrc, int* sDst, int E) {
  const int e = blockIdx.x * 256 + threadIdx.x;
  if (e >= E) return;
  const int d = dst[e];
  const int p = off[d] + atomicAdd(&ctr[d], 1);
  sIdx[p] = e;
  sSrc[p] = src[e];
  sDst[p] = d;
}

// pool over f16 h (f32 accumulation)
__global__ void pool_accum(const f16* __restrict__ h,
                           const int* __restrict__ batch,
                           float* __restrict__ gsum, int M) {
  const int col = threadIdx.x;
  const int r0 = blockIdx.x * 64;
  const int rend = min(r0 + 64, M);
  if (r0 >= M) return;
  float acc = 0.f;
  int cur = batch[r0];
  for (int r = r0; r < rend; ++r) {
    const int b = batch[r];
    if (b != cur) {
      atomicAdd(&gsum[(size_t)cur * HH + col], acc);
      acc = 0.f;
      cur = b;
    }
    acc += (float)h[(size_t)r * HH + col];
  }
  atomicAdd(&gsum[(size_t)cur * HH + col], acc);
}

__global__ void gcnt_kernel(const int* __restrict__ batch, int* gcnt, int n) {
  const int i = blockIdx.x * 256 + threadIdx.x;
  if (i < n) atomicAdd(&gcnt[batch[i]], 1);
}

__global__ void head_kernel(const float* __restrict__ gsum,
                            const int* __restrict__ gcnt,
                            const float* __restrict__ Wh,
                            const float* __restrict__ bh,
                            float* __restrict__ out) {
  const int g = blockIdx.x;
  const int t = threadIdx.x;  // 128 threads
  float v = gsum[(size_t)g * HH + t] * Wh[t];
#pragma unroll
  for (int o = 32; o > 0; o >>= 1) v += __shfl_down(v, o, 64);
  __shared__ float red[2];
  if ((t & 63) == 0) red[t >> 6] = v;
  __syncthreads();
  if (t == 0) {
    const float s = red[0] + red[1];
    const float c = (float)max(gcnt[g], 1);
    out[g] = s / c + bh[0];
  }
}

// ---------------------------------------------------------------------------
extern "C" void kernel_launch(void* const* d_in, const int* in_sizes, int n_in,
                              void* d_out, int out_size, void* d_ws,
                              size_t ws_size, hipStream_t stream) {
  (void)in_sizes; (void)n_in; (void)out_size;
  const float* x = (const float*)d_in[0];
  const int* ei = (const int*)d_in[1];
  const float* ea = (const float*)d_in[2];
  const int* batch = (const int*)d_in[3];
  const float* Wn0 = (const float*)d_in[4];
  const float* bn0 = (const float*)d_in[5];
  const float* We0 = (const float*)d_in[6];
  const float* be0 = (const float*)d_in[7];
  const float* WM = (const float*)d_in[8];
  const float* bM = (const float*)d_in[9];
  const float* WU = (const float*)d_in[10];
  const float* bU = (const float*)d_in[11];
  const float* Wn = (const float*)d_in[12];
  const float* bn = (const float*)d_in[13];
  const float* We = (const float*)d_in[14];
  const float* be = (const float*)d_in[15];
  const float* Wh = (const float*)d_in[16];
  const float* bh = (const float*)d_in[17];

  const int* srcI = ei;       // edge_index[0]
  const int* dstI = ei + EE;  // edge_index[1]

  // workspace carve — ~141 MB (h now f16)
  float* w = (float*)d_ws;
  size_t o = 0;
  f16* h16 = (f16*)(w + o);  o += (size_t)NN * HH / 2;
  float* agg = w + o;  o += (size_t)NN * HH;
  f16* A16 = (f16*)(w + o); o += (size_t)NN * HH / 2;
  f16* B16 = (f16*)(w + o); o += (size_t)NN * HH / 2;
  float* gsum = w + o; o += (size_t)GG * HH;
  float* invc = w + o; o += (size_t)NN;
  int* cnt = (int*)(w + o);  o += (size_t)NN;
  int* gcnt = (int*)(w + o); o += (size_t)GG;
  int* off = (int*)(w + o);  o += (size_t)NN;
  int* ctr = (int*)(w + o);  o += (size_t)NN;
  int* bsum = (int*)(w + o); o += 512;
  int* sIdx = (int*)(w + o); o += (size_t)EE;
  int* sSrc = (int*)(w + o); o += (size_t)EE;
  int* sDst = (int*)(w + o); o += (size_t)EE;
  f16* Wp = (f16*)(w + o);   o += (size_t)22 * HH * TSTR / 2;
  if (o * sizeof(float) > ws_size) return;  // clean diagnosable failure

  auto WB = [&](int i) { return Wp + (size_t)i * HH * TSTR; };

  const dim3 blk(256);
  const int gridN = (NN + BM - 1) / BM;   // 1563
  const int gridE = EE / 128;             // 5000 (128 edges/block)
  const int NBLK = (NN + 255) / 256;      // 391

  hipMemsetAsync(cnt, 0, (size_t)NN * sizeof(int), stream);
  hipMemsetAsync(ctr, 0, (size_t)NN * sizeof(int), stream);
  hipMemsetAsync(gsum, 0, (size_t)GG * HH * sizeof(float), stream);
  hipMemsetAsync(gcnt, 0, (size_t)GG * sizeof(int), stream);

  count_kernel<<<(EE + 255) / 256, blk, 0, stream>>>(dstI, cnt, EE);
  scan_block<<<NBLK, blk, 0, stream>>>(cnt, off, bsum, NN);
  scan_bsum<<<1, dim3(512), 0, stream>>>(bsum, NBLK);
  scan_add<<<NBLK, blk, 0, stream>>>(off, bsum, NN);
  scatter_edges<<<(EE + 255) / 256, blk, 0, stream>>>(dstI, srcI, off, ctr,
                                                      sIdx, sSrc, sDst, EE);
  invcnt_kernel<<<(NN + 255) / 256, blk, 0, stream>>>(cnt, invc, NN);
  prep_w<<<22 * 8, blk, 0, stream>>>(We0, We, WM, Wn0, Wn, WU, Wp);

  // node encoder: h = relu(x @ Wn0 + bn0)   [MFMA, K=64, f16 out]
  gemm_mfma<2><<<gridN, blk, 0, stream>>>(x, WB(6), bn0, (float*)h16, NN,
                                          nullptr, nullptr, nullptr, nullptr);

  for (int l = 0; l < LL; ++l) {
    // fused A/B projections (f16 in/out): A = h@WM1 (dst), B = h@WM2 (src)
    gemm_mfma<4><<<gridN, blk, 0, stream>>>((const float*)h16, WB(7 + l),
                                            nullptr, (float*)A16, NN, nullptr,
                                            nullptr, WB(10 + l), (float*)B16);
    hipMemsetAsync(agg, 0, (size_t)NN * HH * sizeof(float), stream);
    switch (l) {
      case 0:
        msg_k<0><<<gridE, dim3(512), 0, stream>>>(
            ea, WB(0), be0, WB(1), be, WB(3), bM + 0 * HH, A16, B16, sIdx,
            sSrc, sDst, agg);
        break;
      case 1:
        msg_k<1><<<gridE, dim3(512), 0, stream>>>(
            ea, WB(0), be0, WB(1), be, WB(4), bM + 1 * HH, A16, B16, sIdx,
            sSrc, sDst, agg);
        break;
      default:
        msg_k<2><<<gridE, dim3(512), 0, stream>>>(
            ea, WB(0), be0, WB(1), be, WB(5), bM + 2 * HH, A16, B16, sIdx,
            sSrc, sDst, agg);
        break;
    }
    // update: h = relu([h, agg/cnt] @ WU + bU)  [f16 h chunk + f32 agg chunk]
    gemm_mfma<3><<<gridN, blk, 0, stream>>>((const float*)h16,
                                            WB(16 + 2 * l), bU + l * HH,
                                            (float*)h16, NN, agg, invc,
                                            nullptr, nullptr);
    // node linear: h = relu(h @ Wn + bn)   [f16 in/out]
    gemm_mfma<1><<<gridN, blk, 0, stream>>>((const float*)h16, WB(13 + l),
                                            bn + l * HH, (float*)h16, NN,
                                            nullptr, nullptr, nullptr,
                                            nullptr);
  }

  pool_accum<<<gridN, dim3(128), 0, stream>>>(h16, batch, gsum, NN);
  gcnt_kernel<<<(NN + 255) / 256, blk, 0, stream>>>(batch, gcnt, NN);
  head_kernel<<<GG, dim3(128), 0, stream>>>(gsum, gcnt, Wh, bh, (float*)d_out);
}

// Round 13
// 985.220 us; speedup vs baseline: 1.1636x; 1.0507x over previous
//
#include <hip/hip_runtime.h>

#define NN 100000
#define EE 640000
#define GG 256
#define LL 3
#define HH 128

constexpr int BM = 64;   // rows per block (node gemms)
constexpr int BK = 16;   // k-chunk (fp32 gemm, legacy)

typedef _Float16 f16;
typedef f16 f16x8 __attribute__((ext_vector_type(8)));
typedef f16 f16x4 __attribute__((ext_vector_type(4)));
typedef f16 f16x2 __attribute__((ext_vector_type(2)));
typedef float f32x4 __attribute__((ext_vector_type(4)));

// padded row stride (halfs) for transposed weight / activation tiles.
// 136 halfs = 272 B = 68 words; 68 % 32 = 4 -> fragment rows land 4 banks
// apart; a wave's b128 fragment read hits the 8-words/bank optimum.
#define TSTR 136

// async global->LDS, 16 B per lane (gfx950). Dest must be linear in lane
// order: HW uses wave-uniform base + lane*16 (m104). Our staging is a
// straight contiguous copy, so per-lane dst = base + tid*16 is exactly that.
__device__ __forceinline__ void gload_lds16(const void* g, void* l) {
  __builtin_amdgcn_global_load_lds(
      (const __attribute__((address_space(1))) void*)g,
      (__attribute__((address_space(3))) void*)l, 16, 0, 0);
}

// ---------------------------------------------------------------------------
// Weight prep: transpose + fp16-convert + zero-pad ALL weights once into a
// 22-buffer arena of [128 n][TSTR k] halfs (single launch):
//   0:      We0^T          (K=16, msg encoder; k>=16 zero -> K=32 pad works)
//   1..2:   We[l]^T        l=0,1 (msg chain layers)
//   3..5:   WMe[l]^T       = (WM[l] + 2*H*H)^T, l=0..2 (msg projection)
//   6:      Wn0^T          (K=64, node encoder)
//   7..9:   WM1[l]^T       (A projection, dst), l=0..2
//   10..12: WM2[l]^T       (B projection, src)
//   13..15: Wn[l]^T
//   16..21: WU[l]^T        chunks: 16+2l = rows 0..127 (h part),
//                          17+2l = rows 128..255 (agg part)
// ---------------------------------------------------------------------------
__global__ void prep_w(const float* __restrict__ We0,
                       const float* __restrict__ We,
                       const float* __restrict__ WM,
                       const float* __restrict__ Wn0,
                       const float* __restrict__ Wn,
                       const float* __restrict__ WU, f16* __restrict__ out) {
  const int buf = blockIdx.x >> 3;
  const int rowg = blockIdx.x & 7;  // 16 n-rows per block
  const float* src;
  int K;
  if (buf == 0) {
    src = We0; K = 16;
  } else if (buf <= 2) {
    src = We + (size_t)(buf - 1) * HH * HH; K = HH;
  } else if (buf <= 5) {
    src = WM + (size_t)(buf - 3) * 3 * HH * HH + 2 * HH * HH; K = HH;
  } else if (buf == 6) {
    src = Wn0; K = 64;
  } else if (buf <= 9) {
    src = WM + (size_t)(buf - 7) * 3 * HH * HH; K = HH;
  } else if (buf <= 12) {
    src = WM + (size_t)(buf - 10) * 3 * HH * HH + HH * HH; K = HH;
  } else if (buf <= 15) {
    src = Wn + (size_t)(buf - 13) * HH * HH; K = HH;
  } else {
    const int t = buf - 16;
    src = WU + (size_t)(t >> 1) * 2 * HH * HH + (size_t)(t & 1) * HH * HH;
    K = HH;
  }
  f16* dst = out + (size_t)buf * HH * TSTR;
  for (int idx = threadIdx.x; idx < 16 * TSTR; idx += 256) {
    const int n = rowg * 16 + idx / TSTR;
    const int k = idx % TSTR;
    const float v = (k < K) ? src[(size_t)k * HH + n] : 0.f;
    dst[(size_t)n * TSTR + k] = (f16)v;
  }
}

// ---------------------------------------------------------------------------
// Fused node-path kernels via mfma_f32_16x16x32_f16 (r12->r13: dispatch
// fusion; the per-layer chain update->node-linear->A/B-proj is row-local, so
// h'/h'' stay in LDS as f16 between GEMMs — msg_k's relu-chaining pattern).
// 64-row x 128-col tile, 4 waves; fragment layouts (measured m89/m91):
//   A[m][k]: m=lane&15, k=8*(lane>>4)+j   B[k][n]: n=lane&15, same k
//   D[m][n]: n=lane&15, m=4*(lane>>4)+reg
// LDS: Xs [64][TSTR] f16 | Wt [128][TSTR] f16 (V f32 [64][132] aliases Wt
// for the coalesced A/B stores).
//
// fused_enc:            h = relu(x@Wn0+b);   A = h@WM1(0); B = h@WM2(0)
// fused_upd<HAS_AB>:    h' = relu([h,agg/cnt]@WU+bU); h''= relu(h'@Wn+bn);
//                       if HAS_AB: A = h''@WM1(l+1); B = h''@WM2(l+1)
// ---------------------------------------------------------------------------
struct GemmCtx {
  f16* Xs; f16* Wt; float* V;
  int tid, lane, wv, l15, q, m0;
};

__device__ __forceinline__ void ctx_init(GemmCtx& c, char* smem) {
  c.Xs = (f16*)smem;
  c.Wt = (f16*)(smem + 17408);
  c.V = (float*)(smem + 17408);
  c.tid = threadIdx.x;
  c.lane = c.tid & 63;
  c.wv = c.tid >> 6;
  c.l15 = c.lane & 15;
  c.q = c.lane >> 4;
  c.m0 = blockIdx.x * 64;
}

__device__ __forceinline__ void c_stageW(GemmCtx& c, const f16* Wg) {
  const char* g = (const char*)Wg;
  char* l = (char*)c.Wt;
#pragma unroll
  for (int i = 0; i < 8; ++i)
    gload_lds16(g + c.tid * 16 + i * 4096, l + c.tid * 16 + i * 4096);
  if (c.tid < 128) gload_lds16(g + c.tid * 16 + 32768, l + c.tid * 16 + 32768);
}

__device__ __forceinline__ void c_stageXf32(GemmCtx& c, const float* Xp,
                                            int stride, int KC, bool scale,
                                            const float* inv, int M) {
  const int npr = KC >> 2;
  for (int i = c.tid; i < 64 * npr; i += 256) {
    const int row = i / npr;
    const int c4 = (i - row * npr) << 2;
    float4 v = make_float4(0.f, 0.f, 0.f, 0.f);
    if (c.m0 + row < M) {
      v = *(const float4*)(Xp + (size_t)(c.m0 + row) * stride + c4);
      if (scale) {
        const float s = inv[c.m0 + row];
        v.x *= s; v.y *= s; v.z *= s; v.w *= s;
      }
    }
    f16x4 hv;
    hv[0] = (f16)v.x; hv[1] = (f16)v.y; hv[2] = (f16)v.z; hv[3] = (f16)v.w;
    *(f16x4*)&c.Xs[(size_t)row * TSTR + c4] = hv;
  }
}

__device__ __forceinline__ void c_stageX16(GemmCtx& c, const f16* Xp, int M) {
  for (int i = c.tid; i < 1024; i += 256) {
    const int row = i >> 4;
    const int c8 = (i & 15) << 3;
    f16x8 v = {};
    if (c.m0 + row < M) v = *(const f16x8*)(Xp + (size_t)(c.m0 + row) * HH + c8);
    *(f16x8*)&c.Xs[(size_t)row * TSTR + c8] = v;
  }
}

__device__ __forceinline__ void c_mfmaN(GemmCtx& c, f32x4 (&ac)[4][2],
                                        int nk) {
  for (int kk = 0; kk < nk; ++kk) {
    f16x8 a[4], b[2];
#pragma unroll
    for (int mi = 0; mi < 4; ++mi)
      a[mi] = *(const f16x8*)&c.Xs[(size_t)(mi * 16 + c.l15) * TSTR + kk * 32 +
                                   c.q * 8];
#pragma unroll
    for (int ni = 0; ni < 2; ++ni)
      b[ni] = *(const f16x8*)&c.Wt[(size_t)((c.wv * 2 + ni) * 16 + c.l15) *
                                       TSTR +
                                   kk * 32 + c.q * 8];
#pragma unroll
    for (int mi = 0; mi < 4; ++mi)
#pragma unroll
      for (int ni = 0; ni < 2; ++ni)
        ac[mi][ni] = __builtin_amdgcn_mfma_f32_16x16x32_f16(a[mi], b[ni],
                                                            ac[mi][ni], 0, 0,
                                                            0);
  }
}

__device__ __forceinline__ void c_zero(f32x4 (&ac)[4][2]) {
#pragma unroll
  for (int mi = 0; mi < 4; ++mi)
#pragma unroll
    for (int ni = 0; ni < 2; ++ni) {
      f32x4 z = {};
      ac[mi][ni] = z;
    }
}

// bias + relu -> f16 into Xs (activation chaining; D-layout indexed)
__device__ __forceinline__ void c_reluXs(GemmCtx& c, f32x4 (&ac)[4][2],
                                         const float* bias) {
  const float bv0 = bias[c.wv * 32 + c.l15];
  const float bv1 = bias[c.wv * 32 + 16 + c.l15];
#pragma unroll
  for (int mi = 0; mi < 4; ++mi)
#pragma unroll
    for (int ni = 0; ni < 2; ++ni) {
      const float bb = ni ? bv1 : bv0;
#pragma unroll
      for (int rr = 0; rr < 4; ++rr) {
        float v = ac[mi][ni][rr] + bb;
        v = v > 0.f ? v : 0.f;
        c.Xs[(size_t)(mi * 16 + c.q * 4 + rr) * TSTR + c.wv * 32 + ni * 16 +
             c.l15] = (f16)v;
      }
    }
}

__device__ __forceinline__ void c_dumpV(GemmCtx& c, f32x4 (&ac)[4][2]) {
#pragma unroll
  for (int mi = 0; mi < 4; ++mi)
#pragma unroll
    for (int ni = 0; ni < 2; ++ni)
#pragma unroll
      for (int rr = 0; rr < 4; ++rr)
        c.V[(size_t)(mi * 16 + c.q * 4 + rr) * 132 + c.wv * 32 + ni * 16 +
            c.l15] = ac[mi][ni][rr];
}

__device__ __forceinline__ void c_storeV16(GemmCtx& c, f16* op, int M) {
  const int tm = (c.tid >> 4) << 2;
  const int tn = (c.tid & 15) << 3;
#pragma unroll
  for (int i = 0; i < 4; ++i) {
    const int r = c.m0 + tm + i;
    if (r >= M) continue;
    const float* vp = &c.V[(size_t)(tm + i) * 132 + tn];
    f16x8 hv;
#pragma unroll
    for (int j = 0; j < 8; ++j) hv[j] = (f16)vp[j];
    *(f16x8*)(op + (size_t)r * HH + tn) = hv;
  }
}

// store Xs (f16 activations) -> global, coalesced f16x8 per thread
__device__ __forceinline__ void c_storeXs16(GemmCtx& c, f16* op, int M) {
  const int tm = (c.tid >> 4) << 2;
  const int tn = (c.tid & 15) << 3;
#pragma unroll
  for (int i = 0; i < 4; ++i) {
    const int r = c.m0 + tm + i;
    if (r >= M) continue;
    *(f16x8*)(op + (size_t)r * HH + tn) =
        *(const f16x8*)&c.Xs[(size_t)(tm + i) * TSTR + tn];
  }
}

// A/B projection pair from h'' already resident in Xs. Wt reads must be
// retired before entry (caller syncs).
__device__ __forceinline__ void c_projAB(GemmCtx& c, f32x4 (&ac)[4][2],
                                         const f16* WA, const f16* WBp,
                                         f16* A16, f16* B16, int M) {
  c_zero(ac);
  c_mfmaN(c, ac, 4);             // A = h'' @ WA (Wt staged by caller)
  __syncthreads();               // Wt reads done; V may alias
  c_dumpV(c, ac);
  __syncthreads();               // V writes visible
  c_storeV16(c, A16, M);
  __syncthreads();               // V reads done -> Wt reusable
  c_stageW(c, WBp);
  __syncthreads();               // drains WB stage
  c_zero(ac);
  c_mfmaN(c, ac, 4);             // B = h'' @ WB
  __syncthreads();
  c_dumpV(c, ac);
  __syncthreads();
  c_storeV16(c, B16, M);
}

// encoder + A/B(0):  h = relu(x@Wn0+bn0) -> h16; A=h@WA; B=h@WB
__global__ __launch_bounds__(256) void fused_enc(
    const float* __restrict__ x, const f16* __restrict__ Wn0T,
    const float* __restrict__ bn0, f16* __restrict__ h16,
    const f16* __restrict__ WA, const f16* __restrict__ WBp,
    f16* __restrict__ A16, f16* __restrict__ B16, int M) {
  __shared__ __align__(16) char smem[17408 + 34816];
  GemmCtx c; ctx_init(c, smem);
  f32x4 acc[4][2];
  c_zero(acc);
  c_stageW(c, Wn0T);
  c_stageXf32(c, x, 64, 64, false, nullptr, M);
  __syncthreads();
  c_mfmaN(c, acc, 2);            // K=64
  __syncthreads();               // Xs/Wt reads done
  c_reluXs(c, acc, bn0);         // h -> Xs
  c_stageW(c, WA);               // overlaps
  __syncthreads();               // Xs visible + WA staged
  c_storeXs16(c, h16, M);
  c_projAB(c, acc, WA, WBp, A16, B16, M);
}

// per-layer fused: update + node-linear (+ next layer's A/B if HAS_AB)
template <int HAS_AB>
__global__ __launch_bounds__(256) void fused_upd(
    const f16* __restrict__ h, const f16* __restrict__ WU01,
    const float* __restrict__ bU, const float* __restrict__ agg,
    const float* __restrict__ invc, const f16* __restrict__ WnT,
    const float* __restrict__ bn, const f16* __restrict__ WA,
    const f16* __restrict__ WBp, f16* __restrict__ hout,
    f16* __restrict__ A16, f16* __restrict__ B16, int M) {
  __shared__ __align__(16) char smem[17408 + 34816];
  GemmCtx c; ctx_init(c, smem);
  f32x4 acc[4][2];
  c_zero(acc);
  // update chunk 0: h @ WU0
  c_stageW(c, WU01);
  c_stageX16(c, h, M);
  __syncthreads();
  c_mfmaN(c, acc, 4);
  __syncthreads();               // Xs/Wt reads done
  // update chunk 1: (agg*inv) @ WU1
  c_stageW(c, WU01 + (size_t)HH * TSTR);
  c_stageXf32(c, agg, HH, 128, true, invc, M);
  __syncthreads();
  c_mfmaN(c, acc, 4);
  __syncthreads();
  c_reluXs(c, acc, bU);          // h' -> Xs
  c_stageW(c, WnT);              // overlaps (Wt reads retired)
  __syncthreads();
  c_zero(acc);
  c_mfmaN(c, acc, 4);            // h' @ Wn
  __syncthreads();
  c_reluXs(c, acc, bn);          // h'' -> Xs
  if (HAS_AB) c_stageW(c, WA);   // overlaps
  __syncthreads();               // Xs(h'') visible (+WA staged)
  c_storeXs16(c, hout, M);
  if (HAS_AB) c_projAB(c, acc, WA, WBp, A16, B16, M);
}

// ---------------------------------------------------------------------------
// Fused message kernel via MFMA fp16 (fp32 accumulate), edges sorted by dst.
//   t = relu(ea@We0+be0); CHAIN x (t = relu(t@We_s+be_s)); P = t@WMe
//   v = relu(P + A[dst] + B[src] + bM) -> V f32 LDS -> segmented run
//   reduction into agg (boundary atomics + interior stores, r4-verified).
// r10 config (measured 179us/dispatch, best of r8/r10/r11 variants):
// 128 edges/block, 8 waves (512 thr), single-buffered Wc staged via async
// global_load_lds right after the barrier that retires the prior phase's Wc
// reads. Residual ~180us is LDS-read + VALU co-bound (r11 analysis); parked.
// ---------------------------------------------------------------------------
template <int CHAIN>
__global__ __launch_bounds__(512) void msg_k(
    const float* __restrict__ ea, const f16* __restrict__ W0T,
    const float* __restrict__ be0, const f16* __restrict__ WeT,
    const float* __restrict__ beL, const f16* __restrict__ WMeT,
    const float* __restrict__ bMl, const f16* __restrict__ A,
    const f16* __restrict__ B, const int* __restrict__ sIdx,
    const int* __restrict__ sSrc, const int* __restrict__ sDst,
    float* __restrict__ agg) {
  // LDS: Tc [128][TSTR] f16 (34816 B) | Wc [128][TSTR] f16 (34816 B) |
  // dstS int[128] (512 B). Epilogue V [128][129] f32 = 66048 B aliases
  // Tc+Wc (both dead after the projection MFMA); dstS sits above V.
  __shared__ __align__(16) char smem[34816 + 34816 + 512];
  f16* Tc = (f16*)smem;
  f16* Wc = (f16*)(smem + 34816);
  float* V = (float*)smem;  // [128][129] f32, aliases Tc+Wc
  int* dstS = (int*)(smem + 69632);

  const int tid = threadIdx.x;
  const int lane = tid & 63;
  const int wv = tid >> 6;        // wave 0..7
  const int ew = (wv >> 2) * 64;  // edge-row offset of this wave's half
  const int wn = wv & 3;          // N-column group (32 cols)
  const int l15 = lane & 15;
  const int q = lane >> 4;        // 0..3
  const int r0 = blockIdx.x * 128;  // EE % 128 == 0

  auto wptr = [&](int p) -> const f16* {
    if (p == 0) return W0T;
    if (p <= CHAIN) return WeT + (size_t)(p - 1) * HH * TSTR;
    return WMeT;
  };

  // async weight stage: 34816 B = 2176 float4 via global_load_lds width-16
  auto stage_w = [&](const f16* Wg) {
    const char* g = (const char*)Wg;
    char* l = (char*)Wc;
#pragma unroll
    for (int i = 0; i < 4; ++i)
      gload_lds16(g + tid * 16 + i * 8192, l + tid * 16 + i * 8192);
    if (tid < 128) gload_lds16(g + tid * 16 + 32768, l + tid * 16 + 32768);
  };

  // ---- prologue: issue W0 async; stage ea tile as fp16 into Tc ----
  stage_w(wptr(0));
  {
    const int xr = tid >> 2;        // edge 0..127
    const int xc = (tid & 3) << 2;  // col 0,4,8,12
    const int e = sIdx[r0 + xr];
    const float4 v = *(const float4*)(ea + (size_t)e * 16 + xc);
    f16x4 hv;
    hv[0] = (f16)v.x; hv[1] = (f16)v.y; hv[2] = (f16)v.z; hv[3] = (f16)v.w;
    *(f16x4*)&Tc[(size_t)xr * TSTR + xc] = hv;
    f16x4 z = {};
    *(f16x4*)&Tc[(size_t)xr * TSTR + 16 + xc] = z;
    if (tid < 128) dstS[tid] = sDst[r0 + tid];
  }

  f32x4 acc[4][2];

  auto zero_acc = [&]() {
#pragma unroll
    for (int mi = 0; mi < 4; ++mi)
#pragma unroll
      for (int ni = 0; ni < 2; ++ni) {
        f32x4 z = {};
        acc[mi][ni] = z;
      }
  };

  auto mfma_steps = [&](int nk) {  // nk K=32 steps
    for (int kk = 0; kk < nk; ++kk) {
      f16x8 a[4], b[2];
#pragma unroll
      for (int mi = 0; mi < 4; ++mi)
        a[mi] = *(const f16x8*)&Tc[(size_t)(ew + mi * 16 + l15) * TSTR +
                                   kk * 32 + q * 8];
#pragma unroll
      for (int ni = 0; ni < 2; ++ni)
        b[ni] = *(const f16x8*)&Wc[(size_t)((wn * 2 + ni) * 16 + l15) * TSTR +
                                   kk * 32 + q * 8];
#pragma unroll
      for (int mi = 0; mi < 4; ++mi)
#pragma unroll
        for (int ni = 0; ni < 2; ++ni)
          acc[mi][ni] = __builtin_amdgcn_mfma_f32_16x16x32_f16(
              a[mi], b[ni], acc[mi][ni], 0, 0, 0);
    }
  };

  // bias + relu + fp16-convert -> write back into Tc (NO internal barrier;
  // caller brackets with barriers). Runs while the async W stage is in
  // flight, hiding its L2 latency.
  auto relu_body = [&](const float* bias) {
    float bv0 = bias[wn * 32 + l15];
    float bv1 = bias[wn * 32 + 16 + l15];
#pragma unroll
    for (int mi = 0; mi < 4; ++mi)
#pragma unroll
      for (int ni = 0; ni < 2; ++ni) {
        const float bb = ni ? bv1 : bv0;
#pragma unroll
        for (int rr = 0; rr < 4; ++rr) {
          float v = acc[mi][ni][rr] + bb;
          v = v > 0.f ? v : 0.f;
          Tc[(size_t)(ew + mi * 16 + q * 4 + rr) * TSTR + wn * 32 + ni * 16 +
             l15] = (f16)v;
        }
      }
  };

  // ---- phase 0 (encoder): t = relu(ea @ We0 + be0), K=32 zero-padded ----
  zero_acc();
  __syncthreads();               // drains W0 gload + ea stores
  mfma_steps(1);
  __syncthreads();               // Wc reads done
  stage_w(wptr(1));              // async next-phase weights
  relu_body(be0);                // overlaps the loads
  __syncthreads();               // drains; Tc + Wc ready

  // ---- chain: t = relu(t @ We_s + be_s), K=128 ----
#pragma unroll
  for (int s = 0; s < CHAIN; ++s) {
    zero_acc();
    mfma_steps(4);
    __syncthreads();             // Wc/Tc reads done
    stage_w(wptr(s + 2));        // s+2 <= CHAIN+1 = projection
    relu_body(beL + (size_t)s * HH);
    __syncthreads();
  }

  // ---- projection: P = t @ WMe, K=128 ----
  zero_acc();
  mfma_steps(4);
  __syncthreads();  // Wc/Tc reads done; no gloads outstanding; V aliases

  // dump P fragments to V [128][129] f32 (D-layout -> row layout)
#pragma unroll
  for (int mi = 0; mi < 4; ++mi)
#pragma unroll
    for (int ni = 0; ni < 2; ++ni)
#pragma unroll
      for (int rr = 0; rr < 4; ++rr)
        V[(size_t)(ew + mi * 16 + q * 4 + rr) * 129 + wn * 32 + ni * 16 +
          l15] = acc[mi][ni][rr];
  __syncthreads();

  // epilogue: v = relu(P + A[dst] + B[src] + bM), in-place in V (A/B fp16)
  const int tm = (tid >> 4) << 2;   // 0..124 (4-row groups over 128 rows)
  const int tn = (tid & 15) << 3;   // 0..120
  const float4 m0v = *(const float4*)(bMl + tn);
  const float4 m1v = *(const float4*)(bMl + tn + 4);
  const float mv[8] = {m0v.x, m0v.y, m0v.z, m0v.w,
                       m1v.x, m1v.y, m1v.z, m1v.w};
#pragma unroll
  for (int i = 0; i < 4; ++i) {
    const int rr = r0 + tm + i;
    const int d = dstS[tm + i];
    const int s = sSrc[rr];
    const f16x8 a8 = *(const f16x8*)(A + (size_t)d * HH + tn);
    const f16x8 b8 = *(const f16x8*)(B + (size_t)s * HH + tn);
    float* vp = &V[(size_t)(tm + i) * 129 + tn];
#pragma unroll
    for (int j = 0; j < 8; ++j)
      vp[j] = fmaxf(vp[j] + (float)a8[j] + (float)b8[j] + mv[j], 0.f);
  }
  __syncthreads();

  // segmented run reduction (r4-verified): wave-uniform 32-edge strips.
  // Interior runs own ALL edges of their dst (global sort) -> plain store;
  // first/last runs of a strip -> atomicAdd.
  const int c = tid & 127;
  const int h = tid >> 7;  // strip 0..3 (edges h*32 .. h*32+31)
  float racc = 0.f;
  int cur = dstS[h * 32];
  bool first = true;
  for (int e2 = h * 32; e2 < h * 32 + 32; ++e2) {
    const int d = dstS[e2];
    if (d != cur) {
      if (first) {
        atomicAdd(&agg[(size_t)cur * HH + c], racc);
        first = false;
      } else {
        agg[(size_t)cur * HH + c] = racc;
      }
      racc = 0.f;
      cur = d;
    }
    racc += V[(size_t)e2 * 129 + c];
  }
  atomicAdd(&agg[(size_t)cur * HH + c], racc);
}

// ---------------------------------------------------------------------------
__global__ void count_kernel(const int* __restrict__ dst, int* cnt, int E) {
  const int i = blockIdx.x * 256 + threadIdx.x;
  if (i < E) atomicAdd(&cnt[dst[i]], 1);
}

__global__ void invcnt_kernel(const int* __restrict__ cnt, float* inv, int n) {
  const int i = blockIdx.x * 256 + threadIdx.x;
  if (i < n) inv[i] = 1.0f / (float)max(cnt[i], 1);
}

__global__ void scan_block(const int* __restrict__ cnt, int* excl, int* bsum,
                           int n) {
  __shared__ int s[256];
  const int tx = threadIdx.x;
  const int i = blockIdx.x * 256 + tx;
  const int v = (i < n) ? cnt[i] : 0;
  s[tx] = v;
  __syncthreads();
  for (int off = 1; off < 256; off <<= 1) {
    int tv = (tx >= off) ? s[tx - off] : 0;
    __syncthreads();
    s[tx] += tv;
    __syncthreads();
  }
  if (i < n) excl[i] = s[tx] - v;
  if (tx == 255) bsum[blockIdx.x] = s[255];
}

// parallel exclusive scan of the per-block sums (nb <= 512).
__global__ __launch_bounds__(512) void scan_bsum(int* bsum, int nb) {
  __shared__ int s[512];
  const int t = threadIdx.x;
  const int v0 = (t < nb) ? bsum[t] : 0;
  s[t] = v0;
  __syncthreads();
  for (int off = 1; off < 512; off <<= 1) {
    const int tv = (t >= off) ? s[t - off] : 0;
    __syncthreads();
    s[t] += tv;
    __syncthreads();
  }
  if (t < nb) bsum[t] = s[t] - v0;  // exclusive
}

__global__ void scan_add(int* excl, const int* __restrict__ bsum, int n) {
  const int i = blockIdx.x * 256 + threadIdx.x;
  if (i < n) excl[i] += bsum[blockIdx.x];
}

__global__ void scatter_edges(const int* __restrict__ dst,
                              const int* __restrict__ src,
                              const int* __restrict__ off, int* ctr, int* sIdx,
                              int* sSrc, int* sDst, int E) {
  const int e = blockIdx.x * 256 + threadIdx.x;
  if (e >= E) return;
  const int d = dst[e];
  const int p = off[d] + atomicAdd(&ctr[d], 1);
  sIdx[p] = e;
  sSrc[p] = src[e];
  sDst[p] = d;
}

// pool over f16 h (f32 accumulation)
__global__ void pool_accum(const f16* __restrict__ h,
                           const int* __restrict__ batch,
                           float* __restrict__ gsum, int M) {
  const int col = threadIdx.x;
  const int r0 = blockIdx.x * 64;
  const int rend = min(r0 + 64, M);
  if (r0 >= M) return;
  float acc = 0.f;
  int cur = batch[r0];
  for (int r = r0; r < rend; ++r) {
    const int b = batch[r];
    if (b != cur) {
      atomicAdd(&gsum[(size_t)cur * HH + col], acc);
      acc = 0.f;
      cur = b;
    }
    acc += (float)h[(size_t)r * HH + col];
  }
  atomicAdd(&gsum[(size_t)cur * HH + col], acc);
}

__global__ void gcnt_kernel(const int* __restrict__ batch, int* gcnt, int n) {
  const int i = blockIdx.x * 256 + threadIdx.x;
  if (i < n) atomicAdd(&gcnt[batch[i]], 1);
}

__global__ void head_kernel(const float* __restrict__ gsum,
                            const int* __restrict__ gcnt,
                            const float* __restrict__ Wh,
                            const float* __restrict__ bh,
                            float* __restrict__ out) {
  const int g = blockIdx.x;
  const int t = threadIdx.x;  // 128 threads
  float v = gsum[(size_t)g * HH + t] * Wh[t];
#pragma unroll
  for (int o = 32; o > 0; o >>= 1) v += __shfl_down(v, o, 64);
  __shared__ float red[2];
  if ((t & 63) == 0) red[t >> 6] = v;
  __syncthreads();
  if (t == 0) {
    const float s = red[0] + red[1];
    const float c = (float)max(gcnt[g], 1);
    out[g] = s / c + bh[0];
  }
}

// ---------------------------------------------------------------------------
extern "C" void kernel_launch(void* const* d_in, const int* in_sizes, int n_in,
                              void* d_out, int out_size, void* d_ws,
                              size_t ws_size, hipStream_t stream) {
  (void)in_sizes; (void)n_in; (void)out_size;
  const float* x = (const float*)d_in[0];
  const int* ei = (const int*)d_in[1];
  const float* ea = (const float*)d_in[2];
  const int* batch = (const int*)d_in[3];
  const float* Wn0 = (const float*)d_in[4];
  const float* bn0 = (const float*)d_in[5];
  const float* We0 = (const float*)d_in[6];
  const float* be0 = (const float*)d_in[7];
  const float* WM = (const float*)d_in[8];
  const float* bM = (const float*)d_in[9];
  const float* WU = (const float*)d_in[10];
  const float* bU = (const float*)d_in[11];
  const float* Wn = (const float*)d_in[12];
  const float* bn = (const float*)d_in[13];
  const float* We = (const float*)d_in[14];
  const float* be = (const float*)d_in[15];
  const float* Wh = (const float*)d_in[16];
  const float* bh = (const float*)d_in[17];

  const int* srcI = ei;       // edge_index[0]
  const int* dstI = ei + EE;  // edge_index[1]

  // workspace carve — ~141 MB (h f16)
  float* w = (float*)d_ws;
  size_t o = 0;
  f16* h16 = (f16*)(w + o);  o += (size_t)NN * HH / 2;
  float* agg = w + o;  o += (size_t)NN * HH;
  f16* A16 = (f16*)(w + o); o += (size_t)NN * HH / 2;
  f16* B16 = (f16*)(w + o); o += (size_t)NN * HH / 2;
  float* gsum = w + o; o += (size_t)GG * HH;
  float* invc = w + o; o += (size_t)NN;
  int* cnt = (int*)(w + o);  o += (size_t)NN;
  int* gcnt = (int*)(w + o); o += (size_t)GG;
  int* off = (int*)(w + o);  o += (size_t)NN;
  int* ctr = (int*)(w + o);  o += (size_t)NN;
  int* bsum = (int*)(w + o); o += 512;
  int* sIdx = (int*)(w + o); o += (size_t)EE;
  int* sSrc = (int*)(w + o); o += (size_t)EE;
  int* sDst = (int*)(w + o); o += (size_t)EE;
  f16* Wp = (f16*)(w + o);   o += (size_t)22 * HH * TSTR / 2;
  if (o * sizeof(float) > ws_size) return;  // clean diagnosable failure

  auto WB = [&](int i) { return Wp + (size_t)i * HH * TSTR; };

  const dim3 blk(256);
  const int gridN = (NN + BM - 1) / BM;   // 1563
  const int gridE = EE / 128;             // 5000 (128 edges/block)
  const int NBLK = (NN + 255) / 256;      // 391

  hipMemsetAsync(cnt, 0, (size_t)NN * sizeof(int), stream);
  hipMemsetAsync(ctr, 0, (size_t)NN * sizeof(int), stream);
  hipMemsetAsync(gsum, 0, (size_t)GG * HH * sizeof(float), stream);
  hipMemsetAsync(gcnt, 0, (size_t)GG * sizeof(int), stream);

  count_kernel<<<(EE + 255) / 256, blk, 0, stream>>>(dstI, cnt, EE);
  scan_block<<<NBLK, blk, 0, stream>>>(cnt, off, bsum, NN);
  scan_bsum<<<1, dim3(512), 0, stream>>>(bsum, NBLK);
  scan_add<<<NBLK, blk, 0, stream>>>(off, bsum, NN);
  scatter_edges<<<(EE + 255) / 256, blk, 0, stream>>>(dstI, srcI, off, ctr,
                                                      sIdx, sSrc, sDst, EE);
  invcnt_kernel<<<(NN + 255) / 256, blk, 0, stream>>>(cnt, invc, NN);
  prep_w<<<22 * 8, blk, 0, stream>>>(We0, We, WM, Wn0, Wn, WU, Wp);

  // encoder + A/B(0): h = relu(x@Wn0+bn0); A=h@WM1(0); B=h@WM2(0)
  fused_enc<<<gridN, blk, 0, stream>>>(x, WB(6), bn0, h16, WB(7), WB(10),
                                       A16, B16, NN);

  for (int l = 0; l < LL; ++l) {
    hipMemsetAsync(agg, 0, (size_t)NN * HH * sizeof(float), stream);
    switch (l) {
      case 0:
        msg_k<0><<<gridE, dim3(512), 0, stream>>>(
            ea, WB(0), be0, WB(1), be, WB(3), bM + 0 * HH, A16, B16, sIdx,
            sSrc, sDst, agg);
        break;
      case 1:
        msg_k<1><<<gridE, dim3(512), 0, stream>>>(
            ea, WB(0), be0, WB(1), be, WB(4), bM + 1 * HH, A16, B16, sIdx,
            sSrc, sDst, agg);
        break;
      default:
        msg_k<2><<<gridE, dim3(512), 0, stream>>>(
            ea, WB(0), be0, WB(1), be, WB(5), bM + 2 * HH, A16, B16, sIdx,
            sSrc, sDst, agg);
        break;
    }
    // fused: h' = relu([h,agg/cnt]@WU+bU); h'' = relu(h'@Wn+bn);
    //        if l<2: A=h''@WM1(l+1), B=h''@WM2(l+1)
    if (l < LL - 1) {
      fused_upd<1><<<gridN, blk, 0, stream>>>(
          h16, WB(16 + 2 * l), bU + l * HH, agg, invc, WB(13 + l), bn + l * HH,
          WB(7 + l + 1), WB(10 + l + 1), h16, A16, B16, NN);
    } else {
      fused_upd<0><<<gridN, blk, 0, stream>>>(
          h16, WB(16 + 2 * l), bU + l * HH, agg, invc, WB(13 + l), bn + l * HH,
          nullptr, nullptr, h16, nullptr, nullptr, NN);
    }
  }

  pool_accum<<<gridN, dim3(128), 0, stream>>>(h16, batch, gsum, NN);
  gcnt_kernel<<<(NN + 255) / 256, blk, 0, stream>>>(batch, gcnt, NN);
  head_kernel<<<GG, dim3(128), 0, stream>>>(gsum, gcnt, Wh, bh, (float*)d_out);
}